// Round 1
// baseline (3104.884 us; speedup 1.0000x reference)
//
#include <hip/hip_runtime.h>

#define NN 20000      // nodes
#define NE 640000     // edges
#define DIN 256
#define DM  128

// ---------------- CSR build (dst-sorted edge list) ----------------
__global__ void hist_k(const int* __restrict__ dst, int* __restrict__ cnt, int E) {
    int e = blockIdx.x * 256 + threadIdx.x;
    if (e < E) atomicAdd(&cnt[dst[e]], 1);
}

__global__ void scan_k(const int* __restrict__ cnt, int* __restrict__ row_ptr, int n) {
    __shared__ int lds[1024];
    __shared__ int carry;
    int t = threadIdx.x;
    if (t == 0) carry = 0;
    __syncthreads();
    for (int base = 0; base < n; base += 1024) {
        int v = (base + t < n) ? cnt[base + t] : 0;
        lds[t] = v;
        __syncthreads();
        for (int off = 1; off < 1024; off <<= 1) {
            int x = (t >= off) ? lds[t - off] : 0;
            __syncthreads();
            lds[t] += x;
            __syncthreads();
        }
        if (base + t < n) row_ptr[base + t] = carry + lds[t] - v;  // exclusive
        __syncthreads();
        if (t == 0) carry += lds[1023];
        __syncthreads();
    }
    if (t == 0) row_ptr[n] = carry;
}

__global__ void scatter_k(const int* __restrict__ src, const int* __restrict__ dst,
                          const int* __restrict__ row_ptr, int* __restrict__ cnt2,
                          int* __restrict__ csr_src, int E) {
    int e = blockIdx.x * 256 + threadIdx.x;
    if (e < E) {
        int d = dst[e];
        int pos = row_ptr[d] + atomicAdd(&cnt2[d], 1);
        csr_src[pos] = src[e];
    }
}

// ---------------- generic f32 GEMM: C[n,m] = sum_k A[n,k]*W[m,k] + bias[m] ----------------
// A optionally fused with +A2 (for attn + I@Wi.T). blockIdx.z selects one of up to 3
// (W,bias,C) triples (QKV fusion). Tile 64 rows x 64 cols, 256 threads,
// per-thread 8 rows x 2 cols. post: 0 none, 1 relu, 2 selu.
__global__ __launch_bounds__(256, 2)
void gemm_k(const float* __restrict__ A, const float* __restrict__ A2,
            const float* __restrict__ W0, const float* __restrict__ W1, const float* __restrict__ W2,
            const float* __restrict__ b0, const float* __restrict__ b1, const float* __restrict__ b2,
            float* __restrict__ C0, float* __restrict__ C1, float* __restrict__ C2,
            int N, int K, int M, int post)
{
    __shared__ float Al[64 * 128];
    __shared__ float Wl[64 * 128];
    int z = blockIdx.z;
    const float* W   = (z == 0) ? W0 : (z == 1 ? W1 : W2);
    const float* bia = (z == 0) ? b0 : (z == 1 ? b1 : b2);
    float* C         = (z == 0) ? C0 : (z == 1 ? C1 : C2);
    int n0   = blockIdx.x * 64;
    int moff = blockIdx.y * 64;
    int t = threadIdx.x;
    int c2 = t & 31, rg = t >> 5;

    float acc0[8], acc1[8];
#pragma unroll
    for (int r = 0; r < 8; ++r) { acc0[r] = 0.f; acc1[r] = 0.f; }

    for (int koff = 0; koff < K; koff += 128) {
        int kc  = (K - koff < 128) ? (K - koff) : 128;
        int kc4 = kc >> 2;                       // 16 or 32
        int kshift = (kc4 == 32) ? 5 : 4;
        // stage W tile (64 output-cols x kc), XOR-swizzled float4 slots
        for (int f = t; f < (64 << kshift); f += 256) {
            int m = f >> kshift, k4 = f & (kc4 - 1);
            float4 wv = *(const float4*)&W[(size_t)(moff + m) * K + koff + (k4 << 2)];
            *(float4*)&Wl[(m << 7) + (((k4 ^ m) & (kc4 - 1)) << 2)] = wv;
        }
        // stage A tile (64 rows x kc), optional +A2
        for (int f = t; f < (64 << kshift); f += 256) {
            int r = f >> kshift, k4 = f & (kc4 - 1);
            int row = n0 + r;
            float4 av = make_float4(0.f, 0.f, 0.f, 0.f);
            if (row < N) {
                av = *(const float4*)&A[(size_t)row * K + koff + (k4 << 2)];
                if (A2) {
                    float4 a2 = *(const float4*)&A2[(size_t)row * K + koff + (k4 << 2)];
                    av.x += a2.x; av.y += a2.y; av.z += a2.z; av.w += a2.w;
                }
            }
            *(float4*)&Al[(r << 7) + (k4 << 2)] = av;
        }
        __syncthreads();
        int sw = c2 & (kc4 - 1);
        const float4* Wl4 = (const float4*)Wl;
        const float4* Al4 = (const float4*)Al;
#pragma unroll 4
        for (int k4 = 0; k4 < kc4; ++k4) {
            float4 w0 = Wl4[(c2 << 5) + ((k4 ^ sw) & (kc4 - 1))];
            float4 w1 = Wl4[((c2 + 32) << 5) + ((k4 ^ sw) & (kc4 - 1))];
#pragma unroll
            for (int r = 0; r < 8; ++r) {
                float4 a = Al4[((rg * 8 + r) << 5) + k4];
                acc0[r] = fmaf(a.x, w0.x, fmaf(a.y, w0.y, fmaf(a.z, w0.z, fmaf(a.w, w0.w, acc0[r]))));
                acc1[r] = fmaf(a.x, w1.x, fmaf(a.y, w1.y, fmaf(a.z, w1.z, fmaf(a.w, w1.w, acc1[r]))));
            }
        }
        __syncthreads();
    }
    float bv0 = bia ? bia[moff + c2] : 0.f;
    float bv1 = bia ? bia[moff + c2 + 32] : 0.f;
#pragma unroll
    for (int r = 0; r < 8; ++r) {
        int row = n0 + rg * 8 + r;
        if (row < N) {
            float v0 = acc0[r] + bv0;
            float v1 = acc1[r] + bv1;
            if (post == 1) { v0 = fmaxf(v0, 0.f); v1 = fmaxf(v1, 0.f); }
            else if (post == 2) {
                v0 = (v0 > 0.f) ? 1.0507009873554805f * v0 : 1.7580993408473766f * expm1f(v0);
                v1 = (v1 > 0.f) ? 1.0507009873554805f * v1 : 1.7580993408473766f * expm1f(v1);
            }
            C[(size_t)row * M + moff + c2] = v0;
            C[(size_t)row * M + moff + c2 + 32] = v1;
        }
    }
}

// ---------------- edge attention: one wave per dst node ----------------
// lane l owns dims {2l,2l+1}; head = l>>3 (16 dims = 8 lanes); 8-lane shfl reduce.
__global__ __launch_bounds__(256)
void attn_k(const float* __restrict__ Q, const float* __restrict__ K,
            const float* __restrict__ V, const int* __restrict__ row_ptr,
            const int* __restrict__ csr, float* __restrict__ out)
{
    int lane = threadIdx.x & 63;
    int n = blockIdx.x * 4 + (threadIdx.x >> 6);
    const float2* Q2 = (const float2*)Q;
    const float2* K2 = (const float2*)K;
    const float2* V2 = (const float2*)V;
    float2 q = Q2[n * 64 + lane];
    int e0 = row_ptr[n], e1 = row_ptr[n + 1];
    float a0 = 0.f, a1 = 0.f, zacc = 0.f;
    if (e0 < e1) {
        int s = csr[e0];
        float2 kf = K2[s * 64 + lane];
        float2 vf = V2[s * 64 + lane];
        for (int e = e0; e < e1; ++e) {
            float2 kcur = kf, vcur = vf;
            if (e + 1 < e1) {                 // prefetch next edge's rows
                int sn = csr[e + 1];
                kf = K2[sn * 64 + lane];
                vf = V2[sn * 64 + lane];
            }
            float p = q.x * kcur.x + q.y * kcur.y;
            p += __shfl_xor(p, 1);
            p += __shfl_xor(p, 2);
            p += __shfl_xor(p, 4);            // per-head dot (16 dims over 8 lanes)
            float sc = __expf(fminf(fmaxf(p * 0.25f, -10.f), 10.f)) * 0.5f;
            a0 = fmaf(sc, vcur.x, a0);
            a1 = fmaf(sc, vcur.y, a1);
            zacc += sc;                       // group-uniform: equals zn[head]
        }
    }
    float inv = 1.f / (zacc + 1e-6f);
    ((float2*)out)[n * 64 + lane] = make_float2(a0 * inv, a1 * inv);
}

// ---------------- residual add + LayerNorm over 128 dims: one wave per row ----------------
__global__ __launch_bounds__(256)
void ln_k(const float* __restrict__ X, const float* __restrict__ Y,
          const float* __restrict__ g, const float* __restrict__ b, float* __restrict__ O)
{
    int lane = threadIdx.x & 63;
    int n = blockIdx.x * 4 + (threadIdx.x >> 6);
    float2 xv = ((const float2*)X)[n * 64 + lane];
    float2 yv = ((const float2*)Y)[n * 64 + lane];
    float v0 = xv.x + yv.x, v1 = xv.y + yv.y;
    float s = v0 + v1, sq = v0 * v0 + v1 * v1;
#pragma unroll
    for (int off = 1; off < 64; off <<= 1) {
        s  += __shfl_xor(s, off);
        sq += __shfl_xor(sq, off);
    }
    float m   = s * 0.0078125f;               // /128
    float var = sq * 0.0078125f - m * m;
    float rstd = rsqrtf(var + 1e-5f);
    float2 gv = ((const float2*)g)[lane];
    float2 bv = ((const float2*)b)[lane];
    ((float2*)O)[n * 64 + lane] =
        make_float2((v0 - m) * rstd * gv.x + bv.x, (v1 - m) * rstd * gv.y + bv.y);
}

// ---------------- host side ----------------
static inline void gemm1(hipStream_t st, const float* A, const float* A2,
                         const float* W, const float* b, float* C,
                         int N, int K, int M, int post)
{
    dim3 g((N + 63) / 64, M / 64, 1);
    gemm_k<<<g, 256, 0, st>>>(A, A2, W, nullptr, nullptr, b, nullptr, nullptr,
                              C, nullptr, nullptr, N, K, M, post);
}

static inline void gemm3(hipStream_t st, const float* A,
                         const float* W0, const float* b0, float* C0,
                         const float* W1, const float* b1, float* C1,
                         const float* W2, const float* b2, float* C2,
                         int N, int K, int M)
{
    dim3 g((N + 63) / 64, M / 64, 3);
    gemm_k<<<g, 256, 0, st>>>(A, nullptr, W0, W1, W2, b0, b1, b2, C0, C1, C2, N, K, M, 0);
}

extern "C" void kernel_launch(void* const* d_in, const int* in_sizes, int n_in,
                              void* d_out, int out_size, void* d_ws, size_t ws_size,
                              hipStream_t stream)
{
    const float* x    = (const float*)d_in[0];
    const float* Iin  = (const float*)d_in[1];
    const int*   src  = (const int*)d_in[2];
    const int*   dst  = (const int*)d_in[3];
    const float* Wemb = (const float*)d_in[4];
    const float* Wq   = (const float*)d_in[5];  const float* bq  = (const float*)d_in[6];
    const float* Wk   = (const float*)d_in[7];  const float* bk  = (const float*)d_in[8];
    const float* Wv   = (const float*)d_in[9];  const float* bv  = (const float*)d_in[10];
    const float* Wi   = (const float*)d_in[11]; const float* bi  = (const float*)d_in[12];
    const float* Wo   = (const float*)d_in[13]; const float* bo  = (const float*)d_in[14];
    const float* g1   = (const float*)d_in[15]; const float* be1 = (const float*)d_in[16];
    const float* g2   = (const float*)d_in[17]; const float* be2 = (const float*)d_in[18];
    const float* Wf1  = (const float*)d_in[19]; const float* bf1 = (const float*)d_in[20];
    const float* Wf2  = (const float*)d_in[21]; const float* bf2 = (const float*)d_in[22];
    const float* Wm1  = (const float*)d_in[23]; const float* bm1 = (const float*)d_in[24];
    const float* Wm2  = (const float*)d_in[25]; const float* bm2 = (const float*)d_in[26];

    float* F = (float*)d_ws;
    const size_t NF = (size_t)NN * DM;          // 2.56M floats
    float* h    = F;
    float* h2   = F + NF;
    float* Qb   = F + 2 * NF;
    float* Kb   = F + 3 * NF;
    float* Vb   = F + 4 * NF;
    float* attn = F + 5 * NF;
    float* Iw   = F + 6 * NF;
    float* tmp   = Qb;                          // Q dead after attn_k
    float* ffmid = Kb;                          // spans Kb+Vb (N x 256), dead after attn_k
    int* ib      = (int*)(F + 7 * NF);
    int* cnt     = ib;
    int* cnt2    = ib + NN;
    int* row_ptr = ib + 2 * NN;
    int* csr     = ib + 3 * NN + 1;

    // ---- CSR build (once per call; src/dst constant across layers) ----
    hipMemsetAsync(cnt,  0, NN * sizeof(int), stream);
    hipMemsetAsync(cnt2, 0, NN * sizeof(int), stream);
    hist_k<<<(NE + 255) / 256, 256, 0, stream>>>(dst, cnt, NE);
    scan_k<<<1, 1024, 0, stream>>>(cnt, row_ptr, NN);
    scatter_k<<<(NE + 255) / 256, 256, 0, stream>>>(src, dst, row_ptr, cnt2, csr, NE);

    // ---- loop-invariant precompute ----
    gemm1(stream, x,   nullptr, Wemb, nullptr, h,  NN, DIN, DM, 0);   // h = x @ Wemb.T
    gemm1(stream, Iin, nullptr, Wi,   bi,      Iw, NN, 64,  DM, 0);   // Iw = I @ Wi.T + bi

    // ---- 10 shared-weight graph-transformer layers ----
    for (int l = 0; l < 10; ++l) {
        gemm3(stream, h, Wq, bq, Qb, Wk, bk, Kb, Wv, bv, Vb, NN, DM, DM);
        attn_k<<<NN / 4, 256, 0, stream>>>(Qb, Kb, Vb, row_ptr, csr, attn);
        gemm1(stream, attn, Iw, Wo, bo, tmp, NN, DM, DM, 0);          // (attn+Iw) @ Wo.T + bo
        ln_k<<<NN / 4, 256, 0, stream>>>(h, tmp, g1, be1, h2);        // h2 = LN(h + .)
        gemm1(stream, h2, nullptr, Wf1, bf1, ffmid, NN, DM, 2 * DM, 1);  // relu
        gemm1(stream, ffmid, nullptr, Wf2, bf2, tmp, NN, 2 * DM, DM, 0);
        ln_k<<<NN / 4, 256, 0, stream>>>(h2, tmp, g2, be2, h);        // h = LN(h2 + ff)
    }

    // ---- reconstruction head ----
    gemm1(stream, h, nullptr, Wm1, bm1, tmp, NN, DM, DM, 2);          // selu
    float* xhat = (float*)d_out + NF;
    gemm1(stream, tmp, nullptr, Wm2, bm2, xhat, NN, DM, DIN, 0);
    hipMemcpyAsync(d_out, h, NF * sizeof(float), hipMemcpyDeviceToDevice, stream);
}

// Round 2
// 1842.539 us; speedup vs baseline: 1.6851x; 1.6851x over previous
//
#include <hip/hip_runtime.h>
#include <hip/hip_bf16.h>

#define NN 20000      // nodes
#define NE 640000     // edges
#define DIN 256
#define DM  128

typedef __hip_bfloat16 bf16;
typedef __attribute__((ext_vector_type(8))) short s8;     // 8 bf16 (4 VGPRs) MFMA frag
typedef __attribute__((ext_vector_type(4))) float f4;     // 4 f32 acc

__device__ __forceinline__ float bu2f_lo(unsigned u) { union {unsigned u; float f;} c; c.u = u << 16; return c.f; }
__device__ __forceinline__ float bu2f_hi(unsigned u) { union {unsigned u; float f;} c; c.u = u & 0xffff0000u; return c.f; }
__device__ __forceinline__ unsigned short f2bu(float f) { bf16 t = __float2bfloat16(f); return *reinterpret_cast<unsigned short*>(&t); }
__device__ __forceinline__ unsigned pk2(float lo, float hi) { return (unsigned)f2bu(lo) | ((unsigned)f2bu(hi) << 16); }
__device__ __forceinline__ unsigned addpk(unsigned a, unsigned b) {
    return pk2(bu2f_lo(a) + bu2f_lo(b), bu2f_hi(a) + bu2f_hi(b));
}

// ---------------- CSR build (dst-sorted edge list) ----------------
__global__ void hist_k(const int* __restrict__ dst, int* __restrict__ cnt, int E) {
    int e = blockIdx.x * 256 + threadIdx.x;
    if (e < E) atomicAdd(&cnt[dst[e]], 1);
}

__global__ void scan_k(const int* __restrict__ cnt, int* __restrict__ row_ptr, int n) {
    __shared__ int lds[1024];
    __shared__ int carry;
    int t = threadIdx.x;
    if (t == 0) carry = 0;
    __syncthreads();
    for (int base = 0; base < n; base += 1024) {
        int v = (base + t < n) ? cnt[base + t] : 0;
        lds[t] = v;
        __syncthreads();
        for (int off = 1; off < 1024; off <<= 1) {
            int x = (t >= off) ? lds[t - off] : 0;
            __syncthreads();
            lds[t] += x;
            __syncthreads();
        }
        if (base + t < n) row_ptr[base + t] = carry + lds[t] - v;  // exclusive
        __syncthreads();
        if (t == 0) carry += lds[1023];
        __syncthreads();
    }
    if (t == 0) row_ptr[n] = carry;
}

__global__ void scatter_k(const int* __restrict__ src, const int* __restrict__ dst,
                          const int* __restrict__ row_ptr, int* __restrict__ cnt2,
                          int* __restrict__ csr_src, int E) {
    int e = blockIdx.x * 256 + threadIdx.x;
    if (e < E) {
        int d = dst[e];
        int pos = row_ptr[d] + atomicAdd(&cnt2[d], 1);
        csr_src[pos] = src[e];
    }
}

// ---------------- batched f32 -> bf16 convert ----------------
struct Cvt { const float* s[12]; bf16* d[12]; int n[12]; };

__global__ void cvt_many_k(Cvt c) {
    int a = blockIdx.y;
    int n4 = c.n[a] >> 2;                        // all counts divisible by 4
    const float4* s = (const float4*)c.s[a];
    uint2* d = (uint2*)c.d[a];
    for (int i = blockIdx.x * 256 + threadIdx.x; i < n4; i += gridDim.x * 256) {
        float4 v = s[i];
        d[i] = make_uint2(pk2(v.x, v.y), pk2(v.z, v.w));
    }
}

// ---------------- bf16 MFMA GEMM: C[n,m] = sum_k A[n,k]*W[m,k] + bias[m] ----------------
// 64x64 tile, 256 thr (4 waves 2x2), full K (<=256) staged once in LDS with XOR swizzle.
// A2 (optional) added during staging. z selects (W,bias,Cf,Cb) for QKV fusion.
// post: 0 none, 1 relu, 2 selu. Outputs optional f32 and/or bf16.
__global__ __launch_bounds__(256, 2)
void gemm_mfma_k(const bf16* __restrict__ A, const bf16* __restrict__ A2,
                 const bf16* __restrict__ W0, const bf16* __restrict__ W1, const bf16* __restrict__ W2,
                 const float* __restrict__ b0, const float* __restrict__ b1, const float* __restrict__ b2,
                 float* __restrict__ Cf0, float* __restrict__ Cf1, float* __restrict__ Cf2,
                 bf16* __restrict__ Cb0, bf16* __restrict__ Cb1, bf16* __restrict__ Cb2,
                 int N, int K, int M, int post)
{
    __shared__ unsigned short Al[64 * 256];
    __shared__ unsigned short Wl[64 * 256];
    int z = blockIdx.z;
    const bf16* W   = (z == 0) ? W0 : (z == 1 ? W1 : W2);
    const float* bia = (z == 0) ? b0 : (z == 1 ? b1 : b2);
    float* Cf        = (z == 0) ? Cf0 : (z == 1 ? Cf1 : Cf2);
    bf16*  Cb        = (z == 0) ? Cb0 : (z == 1 ? Cb1 : Cb2);
    int n0 = blockIdx.x * 64, moff = blockIdx.y * 64;
    int t = threadIdx.x;
    int ksh = (K == 64) ? 3 : ((K == 128) ? 4 : 5);   // log2(K/8) 16B slots per row
    int k8s = 1 << ksh;
    int slots = 64 << ksh;
    int rowbytes = K * 2;

    // stage W tile: 64 cols x K, 16B slots, XOR-swizzled
    for (int f = t; f < slots; f += 256) {
        int r = f >> ksh, k8 = f & (k8s - 1);
        uint4 wv = *(const uint4*)&W[(size_t)(moff + r) * K + (k8 << 3)];
        int byte = r * rowbytes + (((k8 << 4) ^ ((r & 7) << 4)));
        *(uint4*)((char*)Wl + byte) = wv;
    }
    // stage A tile: 64 rows x K (+ optional A2 add)
    for (int f = t; f < slots; f += 256) {
        int r = f >> ksh, k8 = f & (k8s - 1);
        int row = n0 + r;
        uint4 av = make_uint4(0, 0, 0, 0);
        if (row < N) {
            av = *(const uint4*)&A[(size_t)row * K + (k8 << 3)];
            if (A2) {
                uint4 a2 = *(const uint4*)&A2[(size_t)row * K + (k8 << 3)];
                av.x = addpk(av.x, a2.x); av.y = addpk(av.y, a2.y);
                av.z = addpk(av.z, a2.z); av.w = addpk(av.w, a2.w);
            }
        }
        int byte = r * rowbytes + (((k8 << 4) ^ ((r & 7) << 4)));
        *(uint4*)((char*)Al + byte) = av;
    }
    __syncthreads();

    int lane = t & 63, wid = t >> 6;
    int wr = wid >> 1, wc = wid & 1;
    int lr = lane & 15, lk = lane >> 4;
    f4 acc00 = {0,0,0,0}, acc01 = {0,0,0,0}, acc10 = {0,0,0,0}, acc11 = {0,0,0,0};
    int ar0 = wr * 32 + lr, ar1 = ar0 + 16;
    int wr0 = wc * 32 + lr, wr1 = wr0 + 16;
    const char* Ac = (const char*)Al;
    const char* Wc = (const char*)Wl;
    int nks = K >> 5;
    for (int ks = 0; ks < nks; ++ks) {
        int w = ks * 64 + (lk << 4);
        s8 a0 = *(const s8*)(Ac + ar0 * rowbytes + (w ^ ((ar0 & 7) << 4)));
        s8 a1 = *(const s8*)(Ac + ar1 * rowbytes + (w ^ ((ar1 & 7) << 4)));
        s8 w0 = *(const s8*)(Wc + wr0 * rowbytes + (w ^ ((wr0 & 7) << 4)));
        s8 w1 = *(const s8*)(Wc + wr1 * rowbytes + (w ^ ((wr1 & 7) << 4)));
        acc00 = __builtin_amdgcn_mfma_f32_16x16x32_bf16(a0, w0, acc00, 0, 0, 0);
        acc01 = __builtin_amdgcn_mfma_f32_16x16x32_bf16(a0, w1, acc01, 0, 0, 0);
        acc10 = __builtin_amdgcn_mfma_f32_16x16x32_bf16(a1, w0, acc10, 0, 0, 0);
        acc11 = __builtin_amdgcn_mfma_f32_16x16x32_bf16(a1, w1, acc11, 0, 0, 0);
    }

    float bv0 = bia ? bia[moff + wc * 32 + lr] : 0.f;
    float bv1 = bia ? bia[moff + wc * 32 + 16 + lr] : 0.f;
#pragma unroll
    for (int m = 0; m < 2; ++m) {
#pragma unroll
        for (int n = 0; n < 2; ++n) {
            f4 a = (m == 0) ? (n == 0 ? acc00 : acc01) : (n == 0 ? acc10 : acc11);
            float bv = (n == 0) ? bv0 : bv1;
            int col = moff + wc * 32 + n * 16 + lr;
#pragma unroll
            for (int i = 0; i < 4; ++i) {
                int row = n0 + wr * 32 + m * 16 + lk * 4 + i;
                if (row < N) {
                    float v = a[i] + bv;
                    if (post == 1) v = fmaxf(v, 0.f);
                    else if (post == 2) v = (v > 0.f) ? 1.0507009873554805f * v
                                                      : 1.7580993408473766f * expm1f(v);
                    if (Cf) Cf[(size_t)row * M + col] = v;
                    if (Cb) Cb[(size_t)row * M + col] = __float2bfloat16(v);
                }
            }
        }
    }
}

// ---------------- edge attention (bf16 Q/K/V): one wave per dst node ----------------
// lane l owns dims {2l,2l+1}; head = l>>3; 8-lane shfl reduce for the 16-dim dot.
__global__ __launch_bounds__(256)
void attn_k(const bf16* __restrict__ Q, const bf16* __restrict__ K,
            const bf16* __restrict__ V, const int* __restrict__ row_ptr,
            const int* __restrict__ csr, bf16* __restrict__ out)
{
    int lane = threadIdx.x & 63;
    int n = blockIdx.x * 4 + (threadIdx.x >> 6);
    const unsigned* Q2 = (const unsigned*)Q;
    const unsigned* K2 = (const unsigned*)K;
    const unsigned* V2 = (const unsigned*)V;
    unsigned qu = Q2[n * 64 + lane];
    float qx = bu2f_lo(qu), qy = bu2f_hi(qu);
    int e0 = row_ptr[n], e1 = row_ptr[n + 1];
    float a0 = 0.f, a1 = 0.f, zacc = 0.f;
    if (e0 < e1) {
        int s = csr[e0];
        unsigned ku = K2[s * 64 + lane];
        unsigned vu = V2[s * 64 + lane];
        for (int e = e0; e < e1; ++e) {
            unsigned kc = ku, vc = vu;
            if (e + 1 < e1) {                 // prefetch next edge's rows
                int sn = csr[e + 1];
                ku = K2[sn * 64 + lane];
                vu = V2[sn * 64 + lane];
            }
            float p = qx * bu2f_lo(kc) + qy * bu2f_hi(kc);
            p += __shfl_xor(p, 1);
            p += __shfl_xor(p, 2);
            p += __shfl_xor(p, 4);            // per-head dot (16 dims over 8 lanes)
            float sc = __expf(fminf(fmaxf(p * 0.25f, -10.f), 10.f)) * 0.5f;
            a0 = fmaf(sc, bu2f_lo(vc), a0);
            a1 = fmaf(sc, bu2f_hi(vc), a1);
            zacc += sc;                       // group-uniform: equals zn[head]
        }
    }
    float inv = 1.f / (zacc + 1e-6f);
    ((unsigned*)out)[n * 64 + lane] = pk2(a0 * inv, a1 * inv);
}

// ---------------- residual add + LayerNorm (128 dims): one wave per row ----------------
__global__ __launch_bounds__(256)
void ln_k(const float* __restrict__ X, const float* __restrict__ Y,
          const float* __restrict__ g, const float* __restrict__ b,
          float* __restrict__ O, bf16* __restrict__ Ob)
{
    int lane = threadIdx.x & 63;
    int n = blockIdx.x * 4 + (threadIdx.x >> 6);
    float2 xv = ((const float2*)X)[n * 64 + lane];
    float2 yv = ((const float2*)Y)[n * 64 + lane];
    float v0 = xv.x + yv.x, v1 = xv.y + yv.y;
    float s = v0 + v1, sq = v0 * v0 + v1 * v1;
#pragma unroll
    for (int off = 1; off < 64; off <<= 1) {
        s  += __shfl_xor(s, off);
        sq += __shfl_xor(sq, off);
    }
    float m   = s * 0.0078125f;               // /128
    float var = sq * 0.0078125f - m * m;
    float rstd = rsqrtf(var + 1e-5f);
    float2 gv = ((const float2*)g)[lane];
    float2 bv = ((const float2*)b)[lane];
    float o0 = (v0 - m) * rstd * gv.x + bv.x;
    float o1 = (v1 - m) * rstd * gv.y + bv.y;
    ((float2*)O)[n * 64 + lane] = make_float2(o0, o1);
    ((unsigned*)Ob)[n * 64 + lane] = pk2(o0, o1);
}

// ---------------- host side ----------------
static inline void g1(hipStream_t st, const bf16* A, const bf16* A2, const bf16* W,
                      const float* bia, float* Cf, bf16* Cb, int N, int K, int M, int post)
{
    dim3 grid((N + 63) / 64, M / 64, 1);
    gemm_mfma_k<<<grid, 256, 0, st>>>(A, A2, W, nullptr, nullptr, bia, nullptr, nullptr,
                                      Cf, nullptr, nullptr, Cb, nullptr, nullptr, N, K, M, post);
}

static inline void g3(hipStream_t st, const bf16* A,
                      const bf16* W0, const float* b0, bf16* C0,
                      const bf16* W1, const float* b1, bf16* C1,
                      const bf16* W2, const float* b2, bf16* C2,
                      int N, int K, int M)
{
    dim3 grid((N + 63) / 64, M / 64, 3);
    gemm_mfma_k<<<grid, 256, 0, st>>>(A, nullptr, W0, W1, W2, b0, b1, b2,
                                      nullptr, nullptr, nullptr, C0, C1, C2, N, K, M, 0);
}

extern "C" void kernel_launch(void* const* d_in, const int* in_sizes, int n_in,
                              void* d_out, int out_size, void* d_ws, size_t ws_size,
                              hipStream_t stream)
{
    const float* x    = (const float*)d_in[0];
    const float* Iin  = (const float*)d_in[1];
    const int*   src  = (const int*)d_in[2];
    const int*   dst  = (const int*)d_in[3];
    const float* Wemb = (const float*)d_in[4];
    const float* Wq   = (const float*)d_in[5];  const float* bq  = (const float*)d_in[6];
    const float* Wk   = (const float*)d_in[7];  const float* bk  = (const float*)d_in[8];
    const float* Wv   = (const float*)d_in[9];  const float* bv  = (const float*)d_in[10];
    const float* Wi   = (const float*)d_in[11]; const float* bi  = (const float*)d_in[12];
    const float* Wo   = (const float*)d_in[13]; const float* bo  = (const float*)d_in[14];
    const float* g1g  = (const float*)d_in[15]; const float* be1 = (const float*)d_in[16];
    const float* g2g  = (const float*)d_in[17]; const float* be2 = (const float*)d_in[18];
    const float* Wf1  = (const float*)d_in[19]; const float* bf1 = (const float*)d_in[20];
    const float* Wf2  = (const float*)d_in[21]; const float* bf2 = (const float*)d_in[22];
    const float* Wm1  = (const float*)d_in[23]; const float* bm1 = (const float*)d_in[24];
    const float* Wm2  = (const float*)d_in[25]; const float* bm2 = (const float*)d_in[26];

    const size_t NF = (size_t)NN * DM;          // 2,560,000
    float* F   = (float*)d_ws;
    float* h   = F;
    float* h2  = F + NF;
    float* tmp = F + 2 * NF;
    bf16* B      = (bf16*)(F + 3 * NF);
    bf16* h_b    = B;
    bf16* h2_b   = B + NF;
    bf16* Qb     = B + 2 * NF;
    bf16* Kb     = B + 3 * NF;
    bf16* Vb     = B + 4 * NF;
    bf16* attn_b = B + 5 * NF;
    bf16* Iw_b   = B + 6 * NF;
    bf16* wts    = B + 7 * NF;
    // weight arena offsets (elements)
    bf16* Wemb_b = wts;                 // 32768
    bf16* Wq_b   = wts + 32768;         // 16384
    bf16* Wk_b   = Wq_b + 16384;
    bf16* Wv_b   = Wk_b + 16384;
    bf16* Wo_b   = Wv_b + 16384;
    bf16* Wi_b   = Wo_b + 16384;        // 8192
    bf16* Wf1_b  = Wi_b + 8192;         // 32768
    bf16* Wf2_b  = Wf1_b + 32768;       // 32768
    bf16* Wm1_b  = Wf2_b + 32768;       // 16384
    bf16* Wm2_b  = Wm1_b + 16384;       // 32768
    bf16* wend   = Wm2_b + 32768;
    // aliases over dead regions
    bf16* x_b    = Qb;                  // N x 256, dead after embed GEMM
    bf16* Iin_b  = Vb;                  // N x 64, dead after Iw GEMM
    bf16* ffmid  = Qb;                  // N x 256 (spans Qb+Kb), FF1->FF2 only
    bf16* tmp_b  = Qb;                  // head mid
    int* ib      = (int*)wend;
    int* cnt     = ib;
    int* cnt2    = ib + NN;
    int* row_ptr = ib + 2 * NN;
    int* csr     = ib + 3 * NN + 1;

    // ---- CSR build (once per call) ----
    hipMemsetAsync(cnt,  0, NN * sizeof(int), stream);
    hipMemsetAsync(cnt2, 0, NN * sizeof(int), stream);
    hist_k<<<(NE + 255) / 256, 256, 0, stream>>>(dst, cnt, NE);
    scan_k<<<1, 1024, 0, stream>>>(cnt, row_ptr, NN);
    scatter_k<<<(NE + 255) / 256, 256, 0, stream>>>(src, dst, row_ptr, cnt2, csr, NE);

    // ---- batched f32->bf16 conversion of x, I, and all weights ----
    Cvt c;
    c.s[0] = x;    c.d[0] = x_b;    c.n[0] = NN * DIN;
    c.s[1] = Iin;  c.d[1] = Iin_b;  c.n[1] = NN * 64;
    c.s[2] = Wemb; c.d[2] = Wemb_b; c.n[2] = 32768;
    c.s[3] = Wq;   c.d[3] = Wq_b;   c.n[3] = 16384;
    c.s[4] = Wk;   c.d[4] = Wk_b;   c.n[4] = 16384;
    c.s[5] = Wv;   c.d[5] = Wv_b;   c.n[5] = 16384;
    c.s[6] = Wo;   c.d[6] = Wo_b;   c.n[6] = 16384;
    c.s[7] = Wi;   c.d[7] = Wi_b;   c.n[7] = 8192;
    c.s[8] = Wf1;  c.d[8] = Wf1_b;  c.n[8] = 32768;
    c.s[9] = Wf2;  c.d[9] = Wf2_b;  c.n[9] = 32768;
    c.s[10] = Wm1; c.d[10] = Wm1_b; c.n[10] = 16384;
    c.s[11] = Wm2; c.d[11] = Wm2_b; c.n[11] = 32768;
    cvt_many_k<<<dim3(640, 12), 256, 0, stream>>>(c);

    // ---- loop-invariant precompute ----
    g1(stream, x_b,   nullptr, Wemb_b, nullptr, h, h_b, NN, DIN, DM, 0);  // h = x @ Wemb.T
    g1(stream, Iin_b, nullptr, Wi_b,   bi, nullptr, Iw_b, NN, 64, DM, 0); // Iw = I @ Wi.T + bi

    // ---- 10 shared-weight graph-transformer layers ----
    for (int l = 0; l < 10; ++l) {
        g3(stream, h_b, Wq_b, bq, Qb, Wk_b, bk, Kb, Wv_b, bv, Vb, NN, DM, DM);
        attn_k<<<NN / 4, 256, 0, stream>>>(Qb, Kb, Vb, row_ptr, csr, attn_b);
        g1(stream, attn_b, Iw_b, Wo_b, bo, tmp, nullptr, NN, DM, DM, 0);  // (attn+Iw)@Wo.T+bo
        ln_k<<<NN / 4, 256, 0, stream>>>(h, tmp, g1g, be1, h2, h2_b);
        g1(stream, h2_b, nullptr, Wf1_b, bf1, nullptr, ffmid, NN, DM, 2 * DM, 1);  // relu
        g1(stream, ffmid, nullptr, Wf2_b, bf2, tmp, nullptr, NN, 2 * DM, DM, 0);
        float* hout = (l == 9) ? (float*)d_out : h;   // final h goes straight to output
        ln_k<<<NN / 4, 256, 0, stream>>>(h2, tmp, g2g, be2, hout, h_b);
    }

    // ---- reconstruction head ----
    g1(stream, h_b, nullptr, Wm1_b, bm1, nullptr, tmp_b, NN, DM, DM, 2);  // selu
    float* xhat = (float*)d_out + NF;
    g1(stream, tmp_b, nullptr, Wm2_b, bm2, xhat, nullptr, NN, DM, DIN, 0);
}

// Round 3
// 1544.011 us; speedup vs baseline: 2.0109x; 1.1933x over previous
//
#include <hip/hip_runtime.h>
#include <hip/hip_bf16.h>

#define NN 20000      // nodes
#define NE 640000     // edges
#define DIN 256
#define DM  128

typedef __hip_bfloat16 bf16;
typedef __attribute__((ext_vector_type(8))) short s8;     // 8 bf16 (4 VGPRs) MFMA frag
typedef __attribute__((ext_vector_type(4))) float f4;     // 4 f32 acc

__device__ __forceinline__ float bu2f_lo(unsigned u) { union {unsigned u; float f;} c; c.u = u << 16; return c.f; }
__device__ __forceinline__ float bu2f_hi(unsigned u) { union {unsigned u; float f;} c; c.u = u & 0xffff0000u; return c.f; }
__device__ __forceinline__ unsigned short f2bu(float f) { bf16 t = __float2bfloat16(f); return *reinterpret_cast<unsigned short*>(&t); }
__device__ __forceinline__ unsigned pk2(float lo, float hi) { return (unsigned)f2bu(lo) | ((unsigned)f2bu(hi) << 16); }
__device__ __forceinline__ unsigned addpk(unsigned a, unsigned b) {
    return pk2(bu2f_lo(a) + bu2f_lo(b), bu2f_hi(a) + bu2f_hi(b));
}

// ---------------- CSR build (dst-sorted edge list) ----------------
__global__ void hist_k(const int* __restrict__ dst, int* __restrict__ cnt, int E) {
    int e = blockIdx.x * 256 + threadIdx.x;
    if (e < E) atomicAdd(&cnt[dst[e]], 1);
}

__global__ void scan_k(const int* __restrict__ cnt, int* __restrict__ row_ptr, int n) {
    __shared__ int lds[1024];
    __shared__ int carry;
    int t = threadIdx.x;
    if (t == 0) carry = 0;
    __syncthreads();
    for (int base = 0; base < n; base += 1024) {
        int v = (base + t < n) ? cnt[base + t] : 0;
        lds[t] = v;
        __syncthreads();
        for (int off = 1; off < 1024; off <<= 1) {
            int x = (t >= off) ? lds[t - off] : 0;
            __syncthreads();
            lds[t] += x;
            __syncthreads();
        }
        if (base + t < n) row_ptr[base + t] = carry + lds[t] - v;  // exclusive
        __syncthreads();
        if (t == 0) carry += lds[1023];
        __syncthreads();
    }
    if (t == 0) row_ptr[n] = carry;
}

__global__ void scatter_k(const int* __restrict__ src, const int* __restrict__ dst,
                          const int* __restrict__ row_ptr, int* __restrict__ cnt2,
                          int* __restrict__ csr_src, int E) {
    int e = blockIdx.x * 256 + threadIdx.x;
    if (e < E) {
        int d = dst[e];
        int pos = row_ptr[d] + atomicAdd(&cnt2[d], 1);
        csr_src[pos] = src[e];
    }
}

// ---------------- batched f32 -> bf16 convert ----------------
struct Cvt { const float* s[12]; bf16* d[12]; int n[12]; };

__global__ void cvt_many_k(Cvt c) {
    int a = blockIdx.y;
    int n4 = c.n[a] >> 2;                        // all counts divisible by 4
    const float4* s = (const float4*)c.s[a];
    uint2* d = (uint2*)c.d[a];
    for (int i = blockIdx.x * 256 + threadIdx.x; i < n4; i += gridDim.x * 256) {
        float4 v = s[i];
        d[i] = make_uint2(pk2(v.x, v.y), pk2(v.z, v.w));
    }
}

// ---------------- bf16 MFMA GEMM, 64x128 tile, fused epilogues ----------------
// C[n,m] = sum_k A[n,k]*W[m,k] + bias[m]; A2 (optional) added to A during staging.
// z selects (W,bias,Cb) triple for QKV fusion. grid.y picks 128-col strip of M.
// post: 0 none, 1 relu, 2 selu, 3 residual+LayerNorm (Rf=f32 residual, lng/lnb=gamma/beta;
// requires M==128, grid.y==1). Outputs optional f32 Cf and/or bf16 Cb.
__global__ __launch_bounds__(256, 2)
void gemm_k(const bf16* __restrict__ A, const bf16* __restrict__ A2,
            const bf16* __restrict__ W0, const bf16* __restrict__ W1, const bf16* __restrict__ W2,
            const float* __restrict__ b0, const float* __restrict__ b1, const float* __restrict__ b2,
            float* __restrict__ Cf0, float* __restrict__ Cf1, float* __restrict__ Cf2,
            bf16* __restrict__ Cb0, bf16* __restrict__ Cb1, bf16* __restrict__ Cb2,
            const float* __restrict__ Rf, const float* __restrict__ lng, const float* __restrict__ lnb,
            int N, int K, int M, int post)
{
    __shared__ unsigned short Al[64 * 128];     // 16 KB (max chunk 128)
    __shared__ unsigned short Wl[128 * 128];    // 32 KB
    __shared__ float redS[2][64], redQ[2][64];  // LN cross-wave row stats
    int z = blockIdx.z;
    const bf16* W    = (z == 0) ? W0 : (z == 1 ? W1 : W2);
    const float* bia = (z == 0) ? b0 : (z == 1 ? b1 : b2);
    float* Cf        = (z == 0) ? Cf0 : (z == 1 ? Cf1 : Cf2);
    bf16*  Cb        = (z == 0) ? Cb0 : (z == 1 ? Cb1 : Cb2);
    int n0 = blockIdx.x * 64, moff = blockIdx.y * 128;
    int t = threadIdx.x;
    int lane = t & 63, wid = t >> 6;
    int wr = wid >> 1, wc = wid & 1;            // wave grid 2x2
    int lr = lane & 15, lk = lane >> 4;

    f4 acc[2][4];
#pragma unroll
    for (int m = 0; m < 2; ++m)
#pragma unroll
        for (int n = 0; n < 4; ++n) acc[m][n] = (f4){0.f, 0.f, 0.f, 0.f};

    const char* Ac = (const char*)Al;
    const char* Wc = (const char*)Wl;

    for (int koff = 0; koff < K; koff += 128) {
        int chunk = (K - koff < 128) ? (K - koff) : 128;   // 64 or 128
        int ksh = (chunk == 64) ? 3 : 4;                   // log2(chunk/8)
        int k8s = 1 << ksh;
        int rowb = chunk * 2;                              // bytes per LDS row
        // stage A chunk (64 rows), optional +A2, XOR-swizzled 16B slots
        for (int f = t; f < (64 << ksh); f += 256) {
            int r = f >> ksh, k8 = f & (k8s - 1);
            int row = n0 + r;
            uint4 av = make_uint4(0, 0, 0, 0);
            if (row < N) {
                av = *(const uint4*)&A[(size_t)row * K + koff + (k8 << 3)];
                if (A2) {
                    uint4 a2 = *(const uint4*)&A2[(size_t)row * K + koff + (k8 << 3)];
                    av.x = addpk(av.x, a2.x); av.y = addpk(av.y, a2.y);
                    av.z = addpk(av.z, a2.z); av.w = addpk(av.w, a2.w);
                }
            }
            *(uint4*)((char*)Al + r * rowb + (((k8 << 4)) ^ ((r & 7) << 4))) = av;
        }
        // stage W chunk (128 output-cols)
        for (int f = t; f < (128 << ksh); f += 256) {
            int r = f >> ksh, k8 = f & (k8s - 1);
            uint4 wv = *(const uint4*)&W[(size_t)(moff + r) * K + koff + (k8 << 3)];
            *(uint4*)((char*)Wl + r * rowb + (((k8 << 4)) ^ ((r & 7) << 4))) = wv;
        }
        __syncthreads();
        int nks = chunk >> 5;
        for (int ks = 0; ks < nks; ++ks) {
            int w = ks * 64 + (lk << 4);
            s8 af[2], wf[4];
#pragma unroll
            for (int m = 0; m < 2; ++m) {
                int ar = wr * 32 + m * 16 + lr;
                af[m] = *(const s8*)(Ac + ar * rowb + (w ^ ((ar & 7) << 4)));
            }
#pragma unroll
            for (int n = 0; n < 4; ++n) {
                int wrow = wc * 64 + n * 16 + lr;
                wf[n] = *(const s8*)(Wc + wrow * rowb + (w ^ ((wrow & 7) << 4)));
            }
#pragma unroll
            for (int m = 0; m < 2; ++m)
#pragma unroll
                for (int n = 0; n < 4; ++n)
                    acc[m][n] = __builtin_amdgcn_mfma_f32_16x16x32_bf16(af[m], wf[n], acc[m][n], 0, 0, 0);
        }
        __syncthreads();
    }

    // ---- epilogue ----
    int gcol[4];
#pragma unroll
    for (int n = 0; n < 4; ++n) gcol[n] = moff + wc * 64 + n * 16 + lr;
    float bias_[4];
#pragma unroll
    for (int n = 0; n < 4; ++n) bias_[n] = bia ? bia[gcol[n]] : 0.f;

    if (post == 3) {
        // v = acc + bias + residual; then LN over the 128-wide row
#pragma unroll
        for (int m = 0; m < 2; ++m)
#pragma unroll
            for (int i = 0; i < 4; ++i) {
                int row = n0 + wr * 32 + m * 16 + lk * 4 + i;
                bool ok = row < N;
#pragma unroll
                for (int n = 0; n < 4; ++n) {
                    float r = ok ? Rf[(size_t)row * M + gcol[n]] : 0.f;
                    acc[m][n][i] += bias_[n] + r;
                }
            }
#pragma unroll
        for (int m = 0; m < 2; ++m)
#pragma unroll
            for (int i = 0; i < 4; ++i) {
                float s = acc[m][0][i] + acc[m][1][i] + acc[m][2][i] + acc[m][3][i];
                float q = acc[m][0][i] * acc[m][0][i] + acc[m][1][i] * acc[m][1][i]
                        + acc[m][2][i] * acc[m][2][i] + acc[m][3][i] * acc[m][3][i];
                s += __shfl_xor(s, 1); s += __shfl_xor(s, 2);
                s += __shfl_xor(s, 4); s += __shfl_xor(s, 8);   // reduce over 16 lr lanes
                q += __shfl_xor(q, 1); q += __shfl_xor(q, 2);
                q += __shfl_xor(q, 4); q += __shfl_xor(q, 8);
                if (lr == 0) {
                    int lrow = wr * 32 + m * 16 + lk * 4 + i;
                    redS[wc][lrow] = s;
                    redQ[wc][lrow] = q;
                }
            }
        __syncthreads();
        float gam[4], bet[4];
#pragma unroll
        for (int n = 0; n < 4; ++n) { gam[n] = lng[gcol[n]]; bet[n] = lnb[gcol[n]]; }
#pragma unroll
        for (int m = 0; m < 2; ++m)
#pragma unroll
            for (int i = 0; i < 4; ++i) {
                int lrow = wr * 32 + m * 16 + lk * 4 + i;
                int row = n0 + lrow;
                float s = redS[0][lrow] + redS[1][lrow];
                float q = redQ[0][lrow] + redQ[1][lrow];
                float mean = s * 0.0078125f;                    // /128
                float var  = q * 0.0078125f - mean * mean;
                float rstd = rsqrtf(var + 1e-5f);
                if (row < N) {
#pragma unroll
                    for (int n = 0; n < 4; ++n) {
                        float o = (acc[m][n][i] - mean) * rstd * gam[n] + bet[n];
                        if (Cf) Cf[(size_t)row * M + gcol[n]] = o;
                        if (Cb) Cb[(size_t)row * M + gcol[n]] = __float2bfloat16(o);
                    }
                }
            }
    } else {
#pragma unroll
        for (int m = 0; m < 2; ++m)
#pragma unroll
            for (int i = 0; i < 4; ++i) {
                int row = n0 + wr * 32 + m * 16 + lk * 4 + i;
                if (row < N) {
#pragma unroll
                    for (int n = 0; n < 4; ++n) {
                        float v = acc[m][n][i] + bias_[n];
                        if (post == 1) v = fmaxf(v, 0.f);
                        else if (post == 2) v = (v > 0.f) ? 1.0507009873554805f * v
                                                          : 1.7580993408473766f * expm1f(v);
                        if (Cf) Cf[(size_t)row * M + gcol[n]] = v;
                        if (Cb) Cb[(size_t)row * M + gcol[n]] = __float2bfloat16(v);
                    }
                }
            }
    }
}

// ---------------- edge attention (bf16 Q/K/V): one wave per dst node ----------------
// lane l owns dims {2l,2l+1}; head = l>>3; 8-lane shfl reduce. Prefetch depth 2.
__global__ __launch_bounds__(256)
void attn_k(const bf16* __restrict__ Q, const bf16* __restrict__ K,
            const bf16* __restrict__ V, const int* __restrict__ row_ptr,
            const int* __restrict__ csr, bf16* __restrict__ out)
{
    int lane = threadIdx.x & 63;
    int n = blockIdx.x * 4 + (threadIdx.x >> 6);
    const unsigned* Q2 = (const unsigned*)Q;
    const unsigned* K2 = (const unsigned*)K;
    const unsigned* V2 = (const unsigned*)V;
    unsigned qu = Q2[n * 64 + lane];
    float qx = bu2f_lo(qu), qy = bu2f_hi(qu);
    int e0 = row_ptr[n], e1 = row_ptr[n + 1];
    float a0 = 0.f, a1 = 0.f, zacc = 0.f;
    unsigned k0 = 0, v0 = 0, k1 = 0, v1 = 0;
    if (e0 < e1)     { int s = csr[e0];     k0 = K2[s * 64 + lane]; v0 = V2[s * 64 + lane]; }
    if (e0 + 1 < e1) { int s = csr[e0 + 1]; k1 = K2[s * 64 + lane]; v1 = V2[s * 64 + lane]; }
    for (int e = e0; e < e1; ++e) {
        unsigned kc = k0, vc = v0;
        k0 = k1; v0 = v1;
        if (e + 2 < e1) {                     // keep 2 edges in flight
            int s = csr[e + 2];
            k1 = K2[s * 64 + lane];
            v1 = V2[s * 64 + lane];
        }
        float p = qx * bu2f_lo(kc) + qy * bu2f_hi(kc);
        p += __shfl_xor(p, 1);
        p += __shfl_xor(p, 2);
        p += __shfl_xor(p, 4);                // per-head dot (16 dims over 8 lanes)
        float sc = __expf(fminf(fmaxf(p * 0.25f, -10.f), 10.f)) * 0.5f;
        a0 = fmaf(sc, bu2f_lo(vc), a0);
        a1 = fmaf(sc, bu2f_hi(vc), a1);
        zacc += sc;                           // group-uniform: equals zn[head]
    }
    float inv = 1.f / (zacc + 1e-6f);
    ((unsigned*)out)[n * 64 + lane] = pk2(a0 * inv, a1 * inv);
}

// ---------------- host side ----------------
static inline void g1(hipStream_t st, const bf16* A, const bf16* A2, const bf16* W,
                      const float* bia, float* Cf, bf16* Cb,
                      const float* Rf, const float* lng, const float* lnb,
                      int N, int K, int M, int post)
{
    dim3 grid((N + 63) / 64, M / 128, 1);
    gemm_k<<<grid, 256, 0, st>>>(A, A2, W, nullptr, nullptr, bia, nullptr, nullptr,
                                 Cf, nullptr, nullptr, Cb, nullptr, nullptr,
                                 Rf, lng, lnb, N, K, M, post);
}

static inline void g3(hipStream_t st, const bf16* A,
                      const bf16* W0, const float* b0, bf16* C0,
                      const bf16* W1, const float* b1, bf16* C1,
                      const bf16* W2, const float* b2, bf16* C2,
                      int N, int K, int M)
{
    dim3 grid((N + 63) / 64, M / 128, 3);
    gemm_k<<<grid, 256, 0, st>>>(A, nullptr, W0, W1, W2, b0, b1, b2,
                                 nullptr, nullptr, nullptr, C0, C1, C2,
                                 nullptr, nullptr, nullptr, N, K, M, 0);
}

extern "C" void kernel_launch(void* const* d_in, const int* in_sizes, int n_in,
                              void* d_out, int out_size, void* d_ws, size_t ws_size,
                              hipStream_t stream)
{
    const float* x    = (const float*)d_in[0];
    const float* Iin  = (const float*)d_in[1];
    const int*   src  = (const int*)d_in[2];
    const int*   dst  = (const int*)d_in[3];
    const float* Wemb = (const float*)d_in[4];
    const float* Wq   = (const float*)d_in[5];  const float* bq  = (const float*)d_in[6];
    const float* Wk   = (const float*)d_in[7];  const float* bk  = (const float*)d_in[8];
    const float* Wv   = (const float*)d_in[9];  const float* bv  = (const float*)d_in[10];
    const float* Wi   = (const float*)d_in[11]; const float* bi  = (const float*)d_in[12];
    const float* Wo   = (const float*)d_in[13]; const float* bo  = (const float*)d_in[14];
    const float* g1g  = (const float*)d_in[15]; const float* be1 = (const float*)d_in[16];
    const float* g2g  = (const float*)d_in[17]; const float* be2 = (const float*)d_in[18];
    const float* Wf1  = (const float*)d_in[19]; const float* bf1 = (const float*)d_in[20];
    const float* Wf2  = (const float*)d_in[21]; const float* bf2 = (const float*)d_in[22];
    const float* Wm1  = (const float*)d_in[23]; const float* bm1 = (const float*)d_in[24];
    const float* Wm2  = (const float*)d_in[25]; const float* bm2 = (const float*)d_in[26];

    const size_t NF = (size_t)NN * DM;          // 2,560,000
    float* F  = (float*)d_ws;
    float* h  = F;                              // f32 residual stream
    float* h2 = F + NF;
    bf16* B      = (bf16*)(F + 2 * NF);
    bf16* h_b    = B;
    bf16* h2_b   = B + NF;
    bf16* Qb     = B + 2 * NF;
    bf16* Kb     = B + 3 * NF;
    bf16* Vb     = B + 4 * NF;
    bf16* attn_b = B + 5 * NF;
    bf16* Iw_b   = B + 6 * NF;
    bf16* wts    = B + 7 * NF;
    // weight arena offsets (elements)
    bf16* Wemb_b = wts;                 // 32768
    bf16* Wq_b   = wts + 32768;         // 16384
    bf16* Wk_b   = Wq_b + 16384;
    bf16* Wv_b   = Wk_b + 16384;
    bf16* Wo_b   = Wv_b + 16384;
    bf16* Wi_b   = Wo_b + 16384;        // 8192
    bf16* Wf1_b  = Wi_b + 8192;         // 32768
    bf16* Wf2_b  = Wf1_b + 32768;       // 32768
    bf16* Wm1_b  = Wf2_b + 32768;       // 16384
    bf16* Wm2_b  = Wm1_b + 16384;       // 32768
    bf16* wend   = Wm2_b + 32768;
    // aliases over dead regions
    bf16* x_b    = Qb;                  // N x 256 (spans Qb+Kb), dead before QKV
    bf16* Iin_b  = Vb;                  // N x 64, dead after Iw GEMM
    bf16* ffmid  = Qb;                  // N x 256 (spans Qb+Kb), FF1->FF2 only
    bf16* tmp_b  = Qb;                  // head mid
    int* ib      = (int*)wend;
    int* cnt     = ib;
    int* cnt2    = ib + NN;
    int* row_ptr = ib + 2 * NN;
    int* csr     = ib + 3 * NN + 1;

    // ---- CSR build (once per call) ----
    hipMemsetAsync(cnt,  0, NN * sizeof(int), stream);
    hipMemsetAsync(cnt2, 0, NN * sizeof(int), stream);
    hist_k<<<(NE + 255) / 256, 256, 0, stream>>>(dst, cnt, NE);
    scan_k<<<1, 1024, 0, stream>>>(cnt, row_ptr, NN);
    scatter_k<<<(NE + 255) / 256, 256, 0, stream>>>(src, dst, row_ptr, cnt2, csr, NE);

    // ---- batched f32->bf16 conversion of x, I, and all weights ----
    Cvt c;
    c.s[0] = x;    c.d[0] = x_b;    c.n[0] = NN * DIN;
    c.s[1] = Iin;  c.d[1] = Iin_b;  c.n[1] = NN * 64;
    c.s[2] = Wemb; c.d[2] = Wemb_b; c.n[2] = 32768;
    c.s[3] = Wq;   c.d[3] = Wq_b;   c.n[3] = 16384;
    c.s[4] = Wk;   c.d[4] = Wk_b;   c.n[4] = 16384;
    c.s[5] = Wv;   c.d[5] = Wv_b;   c.n[5] = 16384;
    c.s[6] = Wo;   c.d[6] = Wo_b;   c.n[6] = 16384;
    c.s[7] = Wi;   c.d[7] = Wi_b;   c.n[7] = 8192;
    c.s[8] = Wf1;  c.d[8] = Wf1_b;  c.n[8] = 32768;
    c.s[9] = Wf2;  c.d[9] = Wf2_b;  c.n[9] = 32768;
    c.s[10] = Wm1; c.d[10] = Wm1_b; c.n[10] = 16384;
    c.s[11] = Wm2; c.d[11] = Wm2_b; c.n[11] = 32768;
    cvt_many_k<<<dim3(640, 12), 256, 0, stream>>>(c);

    // ---- loop-invariant precompute ----
    g1(stream, x_b,   nullptr, Wemb_b, nullptr, h, h_b, nullptr, nullptr, nullptr,
       NN, DIN, DM, 0);                                        // h = x @ Wemb.T
    g1(stream, Iin_b, nullptr, Wi_b, bi, nullptr, Iw_b, nullptr, nullptr, nullptr,
       NN, 64, DM, 0);                                         // Iw = I @ Wi.T + bi

    // ---- 10 shared-weight graph-transformer layers ----
    for (int l = 0; l < 10; ++l) {
        g3(stream, h_b, Wq_b, bq, Qb, Wk_b, bk, Kb, Wv_b, bv, Vb, NN, DM, DM);
        attn_k<<<NN / 4, 256, 0, stream>>>(Qb, Kb, Vb, row_ptr, csr, attn_b);
        // h2 = LN(h + (attn+Iw) @ Wo.T + bo)   [fused GEMM + residual + LN]
        g1(stream, attn_b, Iw_b, Wo_b, bo, h2, h2_b, h, g1g, be1, NN, DM, DM, 3);
        // ffmid = relu(h2 @ Wf1.T + bf1)
        g1(stream, h2_b, nullptr, Wf1_b, bf1, nullptr, ffmid, nullptr, nullptr, nullptr,
           NN, DM, 2 * DM, 1);
        // h = LN(h2 + ffmid @ Wf2.T + bf2)     [fused; final layer writes d_out]
        float* hout = (l == 9) ? (float*)d_out : h;
        g1(stream, ffmid, nullptr, Wf2_b, bf2, hout, h_b, h2, g2g, be2, NN, 2 * DM, DM, 3);
    }

    // ---- reconstruction head ----
    g1(stream, h_b, nullptr, Wm1_b, bm1, nullptr, tmp_b, nullptr, nullptr, nullptr,
       NN, DM, DM, 2);                                         // selu
    float* xhat = (float*)d_out + NF;
    g1(stream, tmp_b, nullptr, Wm2_b, bm2, xhat, nullptr, nullptr, nullptr, nullptr,
       NN, DM, DIN, 0);
}

// Round 4
// 1198.590 us; speedup vs baseline: 2.5904x; 1.2882x over previous
//
#include <hip/hip_runtime.h>
#include <hip/hip_bf16.h>

#define NN 20000      // nodes
#define NE 640000     // edges
#define DIN 256
#define DM  128

typedef __hip_bfloat16 bf16;
typedef __attribute__((ext_vector_type(8))) short s8;     // 8 bf16 (4 VGPRs) MFMA frag
typedef __attribute__((ext_vector_type(4))) float f4;     // 4 f32 acc

__device__ __forceinline__ float bu2f_lo(unsigned u) { union {unsigned u; float f;} c; c.u = u << 16; return c.f; }
__device__ __forceinline__ float bu2f_hi(unsigned u) { union {unsigned u; float f;} c; c.u = u & 0xffff0000u; return c.f; }
__device__ __forceinline__ unsigned short f2bu(float f) { bf16 t = __float2bfloat16(f); return *reinterpret_cast<unsigned short*>(&t); }
__device__ __forceinline__ unsigned pk2(float lo, float hi) { return (unsigned)f2bu(lo) | ((unsigned)f2bu(hi) << 16); }
__device__ __forceinline__ unsigned addpk(unsigned a, unsigned b) {
    return pk2(bu2f_lo(a) + bu2f_lo(b), bu2f_hi(a) + bu2f_hi(b));
}
__device__ __forceinline__ void up8(uint4 u, float* f) {
    f[0] = bu2f_lo(u.x); f[1] = bu2f_hi(u.x);
    f[2] = bu2f_lo(u.y); f[3] = bu2f_hi(u.y);
    f[4] = bu2f_lo(u.z); f[5] = bu2f_hi(u.z);
    f[6] = bu2f_lo(u.w); f[7] = bu2f_hi(u.w);
}

// ---------------- CSR build (dst-sorted edge list) ----------------
__global__ void hist_k(const int* __restrict__ dst, int* __restrict__ cnt, int E) {
    int e = blockIdx.x * 256 + threadIdx.x;
    if (e < E) atomicAdd(&cnt[dst[e]], 1);
}

__global__ void scan_k(const int* __restrict__ cnt, int* __restrict__ row_ptr, int n) {
    __shared__ int lds[1024];
    __shared__ int carry;
    int t = threadIdx.x;
    if (t == 0) carry = 0;
    __syncthreads();
    for (int base = 0; base < n; base += 1024) {
        int v = (base + t < n) ? cnt[base + t] : 0;
        lds[t] = v;
        __syncthreads();
        for (int off = 1; off < 1024; off <<= 1) {
            int x = (t >= off) ? lds[t - off] : 0;
            __syncthreads();
            lds[t] += x;
            __syncthreads();
        }
        if (base + t < n) row_ptr[base + t] = carry + lds[t] - v;  // exclusive
        __syncthreads();
        if (t == 0) carry += lds[1023];
        __syncthreads();
    }
    if (t == 0) row_ptr[n] = carry;
}

__global__ void scatter_k(const int* __restrict__ src, const int* __restrict__ dst,
                          const int* __restrict__ row_ptr, int* __restrict__ cnt2,
                          int* __restrict__ csr_src, int E) {
    int e = blockIdx.x * 256 + threadIdx.x;
    if (e < E) {
        int d = dst[e];
        int pos = row_ptr[d] + atomicAdd(&cnt2[d], 1);
        csr_src[pos] = src[e];
    }
}

// ---------------- batched f32 -> bf16 convert ----------------
struct Cvt { const float* s[12]; bf16* d[12]; int n[12]; };

__global__ void cvt_many_k(Cvt c) {
    int a = blockIdx.y;
    int n4 = c.n[a] >> 2;                        // all counts divisible by 4
    const float4* s = (const float4*)c.s[a];
    uint2* d = (uint2*)c.d[a];
    for (int i = blockIdx.x * 256 + threadIdx.x; i < n4; i += gridDim.x * 256) {
        float4 v = s[i];
        d[i] = make_uint2(pk2(v.x, v.y), pk2(v.z, v.w));
    }
}

// ---------------- bf16 MFMA GEMM, 64x128 tile, fused epilogues ----------------
// C[n,m] = sum_k A[n,k]*W[m,k] + bias[m]; A2 (optional) added to A during staging.
// z selects (W,bias,Cb) triple for QKV fusion. grid.y picks 128-col strip of M.
// post: 0 none, 1 relu, 2 selu, 3 residual+LayerNorm (Rb=bf16 residual, lng/lnb
// f32 gamma/beta; requires M==128, grid.y==1). Outputs optional f32 Cf and/or bf16 Cb.
__global__ __launch_bounds__(256, 2)
void gemm_k(const bf16* __restrict__ A, const bf16* __restrict__ A2,
            const bf16* __restrict__ W0, const bf16* __restrict__ W1, const bf16* __restrict__ W2,
            const float* __restrict__ b0, const float* __restrict__ b1, const float* __restrict__ b2,
            float* __restrict__ Cf0, float* __restrict__ Cf1, float* __restrict__ Cf2,
            bf16* __restrict__ Cb0, bf16* __restrict__ Cb1, bf16* __restrict__ Cb2,
            const bf16* __restrict__ Rb, const float* __restrict__ lng, const float* __restrict__ lnb,
            int N, int K, int M, int post)
{
    __shared__ unsigned short Al[64 * 128];     // 16 KB (max chunk 128)
    __shared__ unsigned short Wl[128 * 128];    // 32 KB
    __shared__ float redS[2][64], redQ[2][64];  // LN cross-wave row stats
    int z = blockIdx.z;
    const bf16* W    = (z == 0) ? W0 : (z == 1 ? W1 : W2);
    const float* bia = (z == 0) ? b0 : (z == 1 ? b1 : b2);
    float* Cf        = (z == 0) ? Cf0 : (z == 1 ? Cf1 : Cf2);
    bf16*  Cb        = (z == 0) ? Cb0 : (z == 1 ? Cb1 : Cb2);
    int n0 = blockIdx.x * 64, moff = blockIdx.y * 128;
    int t = threadIdx.x;
    int lane = t & 63, wid = t >> 6;
    int wr = wid >> 1, wc = wid & 1;            // wave grid 2x2
    int lr = lane & 15, lk = lane >> 4;

    f4 acc[2][4];
#pragma unroll
    for (int m = 0; m < 2; ++m)
#pragma unroll
        for (int n = 0; n < 4; ++n) acc[m][n] = (f4){0.f, 0.f, 0.f, 0.f};

    const char* Ac = (const char*)Al;
    const char* Wc = (const char*)Wl;

    for (int koff = 0; koff < K; koff += 128) {
        int chunk = (K - koff < 128) ? (K - koff) : 128;   // 64 or 128
        int ksh = (chunk == 64) ? 3 : 4;                   // log2(chunk/8)
        int k8s = 1 << ksh;
        int rowb = chunk * 2;                              // bytes per LDS row
        // stage A chunk (64 rows), optional +A2, XOR-swizzled 16B slots
        for (int f = t; f < (64 << ksh); f += 256) {
            int r = f >> ksh, k8 = f & (k8s - 1);
            int row = n0 + r;
            uint4 av = make_uint4(0, 0, 0, 0);
            if (row < N) {
                av = *(const uint4*)&A[(size_t)row * K + koff + (k8 << 3)];
                if (A2) {
                    uint4 a2 = *(const uint4*)&A2[(size_t)row * K + koff + (k8 << 3)];
                    av.x = addpk(av.x, a2.x); av.y = addpk(av.y, a2.y);
                    av.z = addpk(av.z, a2.z); av.w = addpk(av.w, a2.w);
                }
            }
            *(uint4*)((char*)Al + r * rowb + (((k8 << 4)) ^ ((r & 7) << 4))) = av;
        }
        // stage W chunk (128 output-cols)
        for (int f = t; f < (128 << ksh); f += 256) {
            int r = f >> ksh, k8 = f & (k8s - 1);
            uint4 wv = *(const uint4*)&W[(size_t)(moff + r) * K + koff + (k8 << 3)];
            *(uint4*)((char*)Wl + r * rowb + (((k8 << 4)) ^ ((r & 7) << 4))) = wv;
        }
        __syncthreads();
        int nks = chunk >> 5;
        for (int ks = 0; ks < nks; ++ks) {
            int w = ks * 64 + (lk << 4);
            s8 af[2], wf[4];
#pragma unroll
            for (int m = 0; m < 2; ++m) {
                int ar = wr * 32 + m * 16 + lr;
                af[m] = *(const s8*)(Ac + ar * rowb + (w ^ ((ar & 7) << 4)));
            }
#pragma unroll
            for (int n = 0; n < 4; ++n) {
                int wrow = wc * 64 + n * 16 + lr;
                wf[n] = *(const s8*)(Wc + wrow * rowb + (w ^ ((wrow & 7) << 4)));
            }
#pragma unroll
            for (int m = 0; m < 2; ++m)
#pragma unroll
                for (int n = 0; n < 4; ++n)
                    acc[m][n] = __builtin_amdgcn_mfma_f32_16x16x32_bf16(af[m], wf[n], acc[m][n], 0, 0, 0);
        }
        __syncthreads();
    }

    // ---- epilogue ----
    int gcol[4];
#pragma unroll
    for (int n = 0; n < 4; ++n) gcol[n] = moff + wc * 64 + n * 16 + lr;
    float bias_[4];
#pragma unroll
    for (int n = 0; n < 4; ++n) bias_[n] = bia ? bia[gcol[n]] : 0.f;

    if (post == 3) {
        // v = acc + bias + residual(bf16); then LN over the 128-wide row
#pragma unroll
        for (int m = 0; m < 2; ++m)
#pragma unroll
            for (int i = 0; i < 4; ++i) {
                int row = n0 + wr * 32 + m * 16 + lk * 4 + i;
                bool ok = row < N;
#pragma unroll
                for (int n = 0; n < 4; ++n) {
                    float r = ok ? __bfloat162float(Rb[(size_t)row * M + gcol[n]]) : 0.f;
                    acc[m][n][i] += bias_[n] + r;
                }
            }
#pragma unroll
        for (int m = 0; m < 2; ++m)
#pragma unroll
            for (int i = 0; i < 4; ++i) {
                float s = acc[m][0][i] + acc[m][1][i] + acc[m][2][i] + acc[m][3][i];
                float q = acc[m][0][i] * acc[m][0][i] + acc[m][1][i] * acc[m][1][i]
                        + acc[m][2][i] * acc[m][2][i] + acc[m][3][i] * acc[m][3][i];
                s += __shfl_xor(s, 1); s += __shfl_xor(s, 2);
                s += __shfl_xor(s, 4); s += __shfl_xor(s, 8);   // reduce over 16 lr lanes
                q += __shfl_xor(q, 1); q += __shfl_xor(q, 2);
                q += __shfl_xor(q, 4); q += __shfl_xor(q, 8);
                if (lr == 0) {
                    int lrow = wr * 32 + m * 16 + lk * 4 + i;
                    redS[wc][lrow] = s;
                    redQ[wc][lrow] = q;
                }
            }
        __syncthreads();
        float gam[4], bet[4];
#pragma unroll
        for (int n = 0; n < 4; ++n) { gam[n] = lng[gcol[n]]; bet[n] = lnb[gcol[n]]; }
#pragma unroll
        for (int m = 0; m < 2; ++m)
#pragma unroll
            for (int i = 0; i < 4; ++i) {
                int lrow = wr * 32 + m * 16 + lk * 4 + i;
                int row = n0 + lrow;
                float s = redS[0][lrow] + redS[1][lrow];
                float q = redQ[0][lrow] + redQ[1][lrow];
                float mean = s * 0.0078125f;                    // /128
                float var  = q * 0.0078125f - mean * mean;
                float rstd = rsqrtf(var + 1e-5f);
                if (row < N) {
#pragma unroll
                    for (int n = 0; n < 4; ++n) {
                        float o = (acc[m][n][i] - mean) * rstd * gam[n] + bet[n];
                        if (Cf) Cf[(size_t)row * M + gcol[n]] = o;
                        if (Cb) Cb[(size_t)row * M + gcol[n]] = __float2bfloat16(o);
                    }
                }
            }
    } else {
#pragma unroll
        for (int m = 0; m < 2; ++m)
#pragma unroll
            for (int i = 0; i < 4; ++i) {
                int row = n0 + wr * 32 + m * 16 + lk * 4 + i;
                if (row < N) {
#pragma unroll
                    for (int n = 0; n < 4; ++n) {
                        float v = acc[m][n][i] + bias_[n];
                        if (post == 1) v = fmaxf(v, 0.f);
                        else if (post == 2) v = (v > 0.f) ? 1.0507009873554805f * v
                                                          : 1.7580993408473766f * expm1f(v);
                        if (Cf) Cf[(size_t)row * M + gcol[n]] = v;
                        if (Cb) Cb[(size_t)row * M + gcol[n]] = __float2bfloat16(v);
                    }
                }
            }
    }
}

// ---------------- edge attention: one wave per dst, 16 lanes per edge ----------------
// Lane = g*16+sub: edge-slot g (4 edges in flight), sub owns dims {8*sub..8*sub+7}
// via one uint4 (16B) load. Head = sub>>1; head-dot closes with one shfl_xor(1).
// Cross-group combine (xor 16/32) once per node.
__global__ __launch_bounds__(256)
void attn_k(const bf16* __restrict__ Q, const bf16* __restrict__ K,
            const bf16* __restrict__ V, const int* __restrict__ row_ptr,
            const int* __restrict__ csr, bf16* __restrict__ out)
{
    int lane = threadIdx.x & 63;
    int n = blockIdx.x * 4 + (threadIdx.x >> 6);
    int g = lane >> 4, sub = lane & 15;
    const uint4* Q4 = (const uint4*)Q;          // 16 uint4 per 128-dim row
    const uint4* K4 = (const uint4*)K;
    const uint4* V4 = (const uint4*)V;
    float q[8];
    up8(Q4[n * 16 + sub], q);
    int e0 = row_ptr[n], e1 = row_ptr[n + 1];
    float acc[8] = {0.f, 0.f, 0.f, 0.f, 0.f, 0.f, 0.f, 0.f};
    float zacc = 0.f;

    int e = e0 + g;
    int s0 = (e < e1) ? csr[e] : 0;
    uint4 k0 = K4[(size_t)s0 * 16 + sub];
    uint4 v0 = V4[(size_t)s0 * 16 + sub];
    for (int base = e0; base < e1; base += 4) {
        int en = base + 4 + g;
        int s1 = (en < e1) ? csr[en] : 0;
        uint4 k1 = K4[(size_t)s1 * 16 + sub];   // next-iter prefetch (wasted on last)
        uint4 v1 = V4[(size_t)s1 * 16 + sub];
        float kf[8];
        up8(k0, kf);
        float p = q[0] * kf[0] + q[1] * kf[1] + q[2] * kf[2] + q[3] * kf[3]
                + q[4] * kf[4] + q[5] * kf[5] + q[6] * kf[6] + q[7] * kf[7];
        p += __shfl_xor(p, 1);                  // close 16-dim head dot (2 lanes/head)
        float sc = __expf(fminf(fmaxf(p * 0.25f, -10.f), 10.f)) * 0.5f;
        if (base + g >= e1) sc = 0.f;           // invalid edge slot
        float vf[8];
        up8(v0, vf);
#pragma unroll
        for (int j = 0; j < 8; ++j) acc[j] = fmaf(sc, vf[j], acc[j]);
        zacc += sc;
        k0 = k1; v0 = v1;
    }
    // combine the 4 edge-groups
#pragma unroll
    for (int j = 0; j < 8; ++j) {
        acc[j] += __shfl_xor(acc[j], 16);
        acc[j] += __shfl_xor(acc[j], 32);
    }
    zacc += __shfl_xor(zacc, 16);
    zacc += __shfl_xor(zacc, 32);
    float inv = 1.f / (zacc + 1e-6f);
    if (g == 0) {
        uint4 o;
        o.x = pk2(acc[0] * inv, acc[1] * inv);
        o.y = pk2(acc[2] * inv, acc[3] * inv);
        o.z = pk2(acc[4] * inv, acc[5] * inv);
        o.w = pk2(acc[6] * inv, acc[7] * inv);
        ((uint4*)out)[n * 16 + sub] = o;
    }
}

// ---------------- host side ----------------
static inline void g1(hipStream_t st, const bf16* A, const bf16* A2, const bf16* W,
                      const float* bia, float* Cf, bf16* Cb,
                      const bf16* Rb, const float* lng, const float* lnb,
                      int N, int K, int M, int post)
{
    dim3 grid((N + 63) / 64, M / 128, 1);
    gemm_k<<<grid, 256, 0, st>>>(A, A2, W, nullptr, nullptr, bia, nullptr, nullptr,
                                 Cf, nullptr, nullptr, Cb, nullptr, nullptr,
                                 Rb, lng, lnb, N, K, M, post);
}

static inline void g3(hipStream_t st, const bf16* A,
                      const bf16* W0, const float* b0, bf16* C0,
                      const bf16* W1, const float* b1, bf16* C1,
                      const bf16* W2, const float* b2, bf16* C2,
                      int N, int K, int M)
{
    dim3 grid((N + 63) / 64, M / 128, 3);
    gemm_k<<<grid, 256, 0, st>>>(A, nullptr, W0, W1, W2, b0, b1, b2,
                                 nullptr, nullptr, nullptr, C0, C1, C2,
                                 nullptr, nullptr, nullptr, N, K, M, 0);
}

extern "C" void kernel_launch(void* const* d_in, const int* in_sizes, int n_in,
                              void* d_out, int out_size, void* d_ws, size_t ws_size,
                              hipStream_t stream)
{
    const float* x    = (const float*)d_in[0];
    const float* Iin  = (const float*)d_in[1];
    const int*   src  = (const int*)d_in[2];
    const int*   dst  = (const int*)d_in[3];
    const float* Wemb = (const float*)d_in[4];
    const float* Wq   = (const float*)d_in[5];  const float* bq  = (const float*)d_in[6];
    const float* Wk   = (const float*)d_in[7];  const float* bk  = (const float*)d_in[8];
    const float* Wv   = (const float*)d_in[9];  const float* bv  = (const float*)d_in[10];
    const float* Wi   = (const float*)d_in[11]; const float* bi  = (const float*)d_in[12];
    const float* Wo   = (const float*)d_in[13]; const float* bo  = (const float*)d_in[14];
    const float* g1g  = (const float*)d_in[15]; const float* be1 = (const float*)d_in[16];
    const float* g2g  = (const float*)d_in[17]; const float* be2 = (const float*)d_in[18];
    const float* Wf1  = (const float*)d_in[19]; const float* bf1 = (const float*)d_in[20];
    const float* Wf2  = (const float*)d_in[21]; const float* bf2 = (const float*)d_in[22];
    const float* Wm1  = (const float*)d_in[23]; const float* bm1 = (const float*)d_in[24];
    const float* Wm2  = (const float*)d_in[25]; const float* bm2 = (const float*)d_in[26];

    const size_t NF = (size_t)NN * DM;          // 2,560,000
    bf16* B      = (bf16*)d_ws;
    bf16* h_b    = B;                           // bf16 residual stream
    bf16* h2_b   = B + NF;
    bf16* Qb     = B + 2 * NF;
    bf16* Kb     = B + 3 * NF;
    bf16* Vb     = B + 4 * NF;
    bf16* attn_b = B + 5 * NF;
    bf16* Iw_b   = B + 6 * NF;
    bf16* wts    = B + 7 * NF;
    // weight arena offsets (elements)
    bf16* Wemb_b = wts;                 // 32768
    bf16* Wq_b   = wts + 32768;         // 16384
    bf16* Wk_b   = Wq_b + 16384;
    bf16* Wv_b   = Wk_b + 16384;
    bf16* Wo_b   = Wv_b + 16384;
    bf16* Wi_b   = Wo_b + 16384;        // 8192
    bf16* Wf1_b  = Wi_b + 8192;         // 32768
    bf16* Wf2_b  = Wf1_b + 32768;       // 32768
    bf16* Wm1_b  = Wf2_b + 32768;       // 16384
    bf16* Wm2_b  = Wm1_b + 16384;       // 32768
    bf16* wend   = Wm2_b + 32768;
    // aliases over dead regions
    bf16* x_b    = Qb;                  // N x 256 (spans Qb+Kb), dead before QKV
    bf16* Iin_b  = Vb;                  // N x 64, dead after Iw GEMM
    bf16* ffmid  = Qb;                  // N x 256 (spans Qb+Kb), FF1->FF2 only
    bf16* tmp_b  = Qb;                  // head mid
    int* ib      = (int*)wend;
    int* cnt     = ib;
    int* cnt2    = ib + NN;
    int* row_ptr = ib + 2 * NN;
    int* csr     = ib + 3 * NN + 1;

    // ---- CSR build (once per call) ----
    hipMemsetAsync(cnt,  0, NN * sizeof(int), stream);
    hipMemsetAsync(cnt2, 0, NN * sizeof(int), stream);
    hist_k<<<(NE + 255) / 256, 256, 0, stream>>>(dst, cnt, NE);
    scan_k<<<1, 1024, 0, stream>>>(cnt, row_ptr, NN);
    scatter_k<<<(NE + 255) / 256, 256, 0, stream>>>(src, dst, row_ptr, cnt2, csr, NE);

    // ---- batched f32->bf16 conversion of x, I, and all weights ----
    Cvt c;
    c.s[0] = x;    c.d[0] = x_b;    c.n[0] = NN * DIN;
    c.s[1] = Iin;  c.d[1] = Iin_b;  c.n[1] = NN * 64;
    c.s[2] = Wemb; c.d[2] = Wemb_b; c.n[2] = 32768;
    c.s[3] = Wq;   c.d[3] = Wq_b;   c.n[3] = 16384;
    c.s[4] = Wk;   c.d[4] = Wk_b;   c.n[4] = 16384;
    c.s[5] = Wv;   c.d[5] = Wv_b;   c.n[5] = 16384;
    c.s[6] = Wo;   c.d[6] = Wo_b;   c.n[6] = 16384;
    c.s[7] = Wi;   c.d[7] = Wi_b;   c.n[7] = 8192;
    c.s[8] = Wf1;  c.d[8] = Wf1_b;  c.n[8] = 32768;
    c.s[9] = Wf2;  c.d[9] = Wf2_b;  c.n[9] = 32768;
    c.s[10] = Wm1; c.d[10] = Wm1_b; c.n[10] = 16384;
    c.s[11] = Wm2; c.d[11] = Wm2_b; c.n[11] = 32768;
    cvt_many_k<<<dim3(640, 12), 256, 0, stream>>>(c);

    // ---- loop-invariant precompute ----
    g1(stream, x_b,   nullptr, Wemb_b, nullptr, nullptr, h_b, nullptr, nullptr, nullptr,
       NN, DIN, DM, 0);                                        // h = x @ Wemb.T
    g1(stream, Iin_b, nullptr, Wi_b, bi, nullptr, Iw_b, nullptr, nullptr, nullptr,
       NN, 64, DM, 0);                                         // Iw = I @ Wi.T + bi

    // ---- 10 shared-weight graph-transformer layers ----
    for (int l = 0; l < 10; ++l) {
        g3(stream, h_b, Wq_b, bq, Qb, Wk_b, bk, Kb, Wv_b, bv, Vb, NN, DM, DM);
        attn_k<<<NN / 4, 256, 0, stream>>>(Qb, Kb, Vb, row_ptr, csr, attn_b);
        // h2 = LN(h + (attn+Iw) @ Wo.T + bo)   [fused GEMM + residual + LN]
        g1(stream, attn_b, Iw_b, Wo_b, bo, nullptr, h2_b, h_b, g1g, be1, NN, DM, DM, 3);
        // ffmid = relu(h2 @ Wf1.T + bf1)
        g1(stream, h2_b, nullptr, Wf1_b, bf1, nullptr, ffmid, nullptr, nullptr, nullptr,
           NN, DM, 2 * DM, 1);
        // h = LN(h2 + ffmid @ Wf2.T + bf2)     [fused; final layer also writes f32 d_out]
        float* hout = (l == 9) ? (float*)d_out : nullptr;
        g1(stream, ffmid, nullptr, Wf2_b, bf2, hout, h_b, h2_b, g2g, be2, NN, 2 * DM, DM, 3);
    }

    // ---- reconstruction head ----
    g1(stream, h_b, nullptr, Wm1_b, bm1, nullptr, tmp_b, nullptr, nullptr, nullptr,
       NN, DM, DM, 2);                                         // selu
    float* xhat = (float*)d_out + NF;
    g1(stream, tmp_b, nullptr, Wm2_b, bm2, xhat, nullptr, nullptr, nullptr, nullptr,
       NN, DM, DIN, 0);
}

// Round 5
// 1008.837 us; speedup vs baseline: 3.0777x; 1.1881x over previous
//
#include <hip/hip_runtime.h>
#include <hip/hip_bf16.h>

#define NN 20000      // nodes
#define NE 640000     // edges
#define DIN 256
#define DM  128

typedef __hip_bfloat16 bf16;
typedef __attribute__((ext_vector_type(8))) short s8;     // 8 bf16 (4 VGPRs) MFMA frag
typedef __attribute__((ext_vector_type(4))) float f4;     // 4 f32 acc

__device__ __forceinline__ float bu2f_lo(unsigned u) { union {unsigned u; float f;} c; c.u = u << 16; return c.f; }
__device__ __forceinline__ float bu2f_hi(unsigned u) { union {unsigned u; float f;} c; c.u = u & 0xffff0000u; return c.f; }
__device__ __forceinline__ unsigned short f2bu(float f) { bf16 t = __float2bfloat16(f); return *reinterpret_cast<unsigned short*>(&t); }
__device__ __forceinline__ unsigned pk2(float lo, float hi) { return (unsigned)f2bu(lo) | ((unsigned)f2bu(hi) << 16); }
__device__ __forceinline__ unsigned addpk(unsigned a, unsigned b) {
    return pk2(bu2f_lo(a) + bu2f_lo(b), bu2f_hi(a) + bu2f_hi(b));
}
__device__ __forceinline__ void up8(uint4 u, float* f) {
    f[0] = bu2f_lo(u.x); f[1] = bu2f_hi(u.x);
    f[2] = bu2f_lo(u.y); f[3] = bu2f_hi(u.y);
    f[4] = bu2f_lo(u.z); f[5] = bu2f_hi(u.z);
    f[6] = bu2f_lo(u.w); f[7] = bu2f_hi(u.w);
}

// ---------------- CSR build (dst-sorted edge list) ----------------
__global__ void hist_k(const int* __restrict__ dst, int* __restrict__ cnt, int E) {
    int e = blockIdx.x * 256 + threadIdx.x;
    if (e < E) atomicAdd(&cnt[dst[e]], 1);
}

__global__ void scan_k(const int* __restrict__ cnt, int* __restrict__ row_ptr, int n) {
    __shared__ int lds[1024];
    __shared__ int carry;
    int t = threadIdx.x;
    if (t == 0) carry = 0;
    __syncthreads();
    for (int base = 0; base < n; base += 1024) {
        int v = (base + t < n) ? cnt[base + t] : 0;
        lds[t] = v;
        __syncthreads();
        for (int off = 1; off < 1024; off <<= 1) {
            int x = (t >= off) ? lds[t - off] : 0;
            __syncthreads();
            lds[t] += x;
            __syncthreads();
        }
        if (base + t < n) row_ptr[base + t] = carry + lds[t] - v;  // exclusive
        __syncthreads();
        if (t == 0) carry += lds[1023];
        __syncthreads();
    }
    if (t == 0) row_ptr[n] = carry;
}

__global__ void scatter_k(const int* __restrict__ src, const int* __restrict__ dst,
                          const int* __restrict__ row_ptr, int* __restrict__ cnt2,
                          int* __restrict__ csr_src, int E) {
    int e = blockIdx.x * 256 + threadIdx.x;
    if (e < E) {
        int d = dst[e];
        int pos = row_ptr[d] + atomicAdd(&cnt2[d], 1);
        csr_src[pos] = src[e];
    }
}

// ---------------- batched f32 -> bf16 convert ----------------
struct Cvt { const float* s[12]; bf16* d[12]; int n[12]; };

__global__ void cvt_many_k(Cvt c) {
    int a = blockIdx.y;
    int n4 = c.n[a] >> 2;                        // all counts divisible by 4
    const float4* s = (const float4*)c.s[a];
    uint2* d = (uint2*)c.d[a];
    for (int i = blockIdx.x * 256 + threadIdx.x; i < n4; i += gridDim.x * 256) {
        float4 v = s[i];
        d[i] = make_uint2(pk2(v.x, v.y), pk2(v.z, v.w));
    }
}

// ---------------- shared GEMM helpers ----------------
// MFMA tile: out rows wr*32+{0..31}, cols wc*(NF*16)+{0..NF*16}. A,W in LDS,
// XOR-swizzled 16B slots, same row-bytes both sides.
template<int NF, int NKS>
__device__ __forceinline__ void mm_tile(const char* A, const char* W, int rowb,
                                        int wr, int wc, int lr, int lk,
                                        f4 (&acc)[2][NF])
{
#pragma unroll
    for (int ks = 0; ks < NKS; ++ks) {
        int w = ks * 64 + (lk << 4);
        s8 af[2], wf[NF];
#pragma unroll
        for (int m = 0; m < 2; ++m) {
            int ar = wr * 32 + m * 16 + lr;
            af[m] = *(const s8*)(A + ar * rowb + (w ^ ((ar & 7) << 4)));
        }
#pragma unroll
        for (int n = 0; n < NF; ++n) {
            int wrow = wc * (NF << 4) + n * 16 + lr;
            wf[n] = *(const s8*)(W + wrow * rowb + (w ^ ((wrow & 7) << 4)));
        }
#pragma unroll
        for (int m = 0; m < 2; ++m)
#pragma unroll
            for (int n = 0; n < NF; ++n)
                acc[m][n] = __builtin_amdgcn_mfma_f32_16x16x32_bf16(af[m], wf[n], acc[m][n], 0, 0, 0);
    }
}

// stage weight tile R rows x KK cols (bf16 row-major) into LDS, swizzled. 512 thr.
template<int R, int KK>
__device__ __forceinline__ void stage_w(char* dst, const bf16* __restrict__ W, int t) {
    constexpr int K8 = KK / 8;
    constexpr int SH = (K8 == 16) ? 4 : 5;
#pragma unroll 2
    for (int f = t; f < R * K8; f += 512) {
        int r = f >> SH, k8 = f & (K8 - 1);
        uint4 wv = *(const uint4*)&W[(size_t)r * KK + (k8 << 3)];
        *(uint4*)(dst + r * (KK * 2) + ((k8 << 4) ^ ((r & 7) << 4))) = wv;
    }
}

// ---------------- bf16 MFMA GEMM, 64x128 tile (prologue / head) ----------------
// post: 0 none, 1 relu, 2 selu. z selects (W,bias,C) for QKV fusion.
__global__ __launch_bounds__(256, 2)
void gemm_k(const bf16* __restrict__ A, const bf16* __restrict__ A2,
            const bf16* __restrict__ W0, const bf16* __restrict__ W1, const bf16* __restrict__ W2,
            const float* __restrict__ b0, const float* __restrict__ b1, const float* __restrict__ b2,
            float* __restrict__ Cf0,
            bf16* __restrict__ Cb0, bf16* __restrict__ Cb1, bf16* __restrict__ Cb2,
            int N, int K, int M, int post)
{
    __shared__ unsigned short Al[64 * 128];
    __shared__ unsigned short Wl[128 * 128];
    int z = blockIdx.z;
    const bf16* W    = (z == 0) ? W0 : (z == 1 ? W1 : W2);
    const float* bia = (z == 0) ? b0 : (z == 1 ? b1 : b2);
    bf16*  Cb        = (z == 0) ? Cb0 : (z == 1 ? Cb1 : Cb2);
    float* Cf        = (z == 0) ? Cf0 : nullptr;
    int n0 = blockIdx.x * 64, moff = blockIdx.y * 128;
    int t = threadIdx.x;
    int lane = t & 63, wid = t >> 6;
    int wr = wid >> 1, wc = wid & 1;            // wave grid 2x2
    int lr = lane & 15, lk = lane >> 4;

    f4 acc[2][4];
#pragma unroll
    for (int m = 0; m < 2; ++m)
#pragma unroll
        for (int n = 0; n < 4; ++n) acc[m][n] = (f4){0.f, 0.f, 0.f, 0.f};

    const char* Ac = (const char*)Al;
    const char* Wc = (const char*)Wl;

    for (int koff = 0; koff < K; koff += 128) {
        int chunk = (K - koff < 128) ? (K - koff) : 128;   // 64 or 128
        int ksh = (chunk == 64) ? 3 : 4;
        int k8s = 1 << ksh;
        int rowb = chunk * 2;
        for (int f = t; f < (64 << ksh); f += 256) {
            int r = f >> ksh, k8 = f & (k8s - 1);
            int row = n0 + r;
            uint4 av = make_uint4(0, 0, 0, 0);
            if (row < N) {
                av = *(const uint4*)&A[(size_t)row * K + koff + (k8 << 3)];
                if (A2) {
                    uint4 a2 = *(const uint4*)&A2[(size_t)row * K + koff + (k8 << 3)];
                    av.x = addpk(av.x, a2.x); av.y = addpk(av.y, a2.y);
                    av.z = addpk(av.z, a2.z); av.w = addpk(av.w, a2.w);
                }
            }
            *(uint4*)((char*)Al + r * rowb + ((k8 << 4) ^ ((r & 7) << 4))) = av;
        }
        for (int f = t; f < (128 << ksh); f += 256) {
            int r = f >> ksh, k8 = f & (k8s - 1);
            uint4 wv = *(const uint4*)&W[(size_t)(moff + r) * K + koff + (k8 << 3)];
            *(uint4*)((char*)Wl + r * rowb + ((k8 << 4) ^ ((r & 7) << 4))) = wv;
        }
        __syncthreads();
        int nks = chunk >> 5;
        for (int ks = 0; ks < nks; ++ks) {
            int w = ks * 64 + (lk << 4);
            s8 af[2], wf[4];
#pragma unroll
            for (int m = 0; m < 2; ++m) {
                int ar = wr * 32 + m * 16 + lr;
                af[m] = *(const s8*)(Ac + ar * rowb + (w ^ ((ar & 7) << 4)));
            }
#pragma unroll
            for (int n = 0; n < 4; ++n) {
                int wrow = wc * 64 + n * 16 + lr;
                wf[n] = *(const s8*)(Wc + wrow * rowb + (w ^ ((wrow & 7) << 4)));
            }
#pragma unroll
            for (int m = 0; m < 2; ++m)
#pragma unroll
                for (int n = 0; n < 4; ++n)
                    acc[m][n] = __builtin_amdgcn_mfma_f32_16x16x32_bf16(af[m], wf[n], acc[m][n], 0, 0, 0);
        }
        __syncthreads();
    }

    int gcol[4];
#pragma unroll
    for (int n = 0; n < 4; ++n) gcol[n] = moff + wc * 64 + n * 16 + lr;
    float bias_[4];
#pragma unroll
    for (int n = 0; n < 4; ++n) bias_[n] = bia ? bia[gcol[n]] : 0.f;
#pragma unroll
    for (int m = 0; m < 2; ++m)
#pragma unroll
        for (int i = 0; i < 4; ++i) {
            int row = n0 + wr * 32 + m * 16 + lk * 4 + i;
            if (row < N) {
#pragma unroll
                for (int n = 0; n < 4; ++n) {
                    float v = acc[m][n][i] + bias_[n];
                    if (post == 1) v = fmaxf(v, 0.f);
                    else if (post == 2) v = (v > 0.f) ? 1.0507009873554805f * v
                                                      : 1.7580993408473766f * expm1f(v);
                    if (Cf) Cf[(size_t)row * M + gcol[n]] = v;
                    if (Cb) Cb[(size_t)row * M + gcol[n]] = __float2bfloat16(v);
                }
            }
        }
}

// ---------------- mega-fused layer kernel ----------------
// Per 64-row block: h2 = LN1(h + (attn+Iw)@Wo^T + bo); ff = relu(h2@Wf1^T+bf1)@Wf2^T+bf2;
// h_new = LN2(h2 + ff)  [h2 residual kept in registers]; optionally QKV for next layer.
// 512 threads = 8 waves (2 row-groups x 4 col-groups). Dynamic LDS 114688 B:
//   [0,16K)   A_in -> h2 -> h_new       (rowb 256)
//   [16K,80K) Wo(32K)/Wf1(64K)/Wf2(64K)/Wq+Wk (phase-dependent)
//   [80K,112K) ffmid (rowb 512) / Wv
__global__ __launch_bounds__(512, 1)
void layer_k(const bf16* __restrict__ attn_b, const bf16* __restrict__ Iw,
             bf16* __restrict__ hres, float* __restrict__ hout_f,
             bf16* __restrict__ Qo, bf16* __restrict__ Ko, bf16* __restrict__ Vo, int doQKV,
             const bf16* __restrict__ Wo, const float* __restrict__ bo,
             const bf16* __restrict__ Wf1, const float* __restrict__ bf1,
             const bf16* __restrict__ Wf2, const float* __restrict__ bf2,
             const bf16* __restrict__ Wq, const float* __restrict__ bqv,
             const bf16* __restrict__ Wk, const float* __restrict__ bkv,
             const bf16* __restrict__ Wv, const float* __restrict__ bvv,
             const float* __restrict__ g1v, const float* __restrict__ b1v,
             const float* __restrict__ g2v, const float* __restrict__ b2v)
{
    extern __shared__ char sm[];
    __shared__ float redS[4][64], redQ[4][64];
    char* smA = sm;                 // 16 KB
    char* smW = sm + 16384;         // up to 96 KB
    char* smF = sm + 81920;         // 32 KB

    int n0 = blockIdx.x * 64;
    int t = threadIdx.x;
    int lane = t & 63, wid = t >> 6;
    int wr = wid >> 2, wc = wid & 3;            // 2 x 4 wave grid
    int lr = lane & 15, lk = lane >> 4;
    int gcol[2] = { wc * 32 + lr, wc * 32 + 16 + lr };
    int lrow[2][4];
#pragma unroll
    for (int m = 0; m < 2; ++m)
#pragma unroll
        for (int i = 0; i < 4; ++i) lrow[m][i] = wr * 32 + m * 16 + lk * 4 + i;

    // ---- phase 1: stage A_in = attn + Iw, Wo ----
    for (int f = t; f < 64 * 16; f += 512) {
        int r = f >> 4, k8 = f & 15;
        int row = n0 + r;
        uint4 av = make_uint4(0, 0, 0, 0);
        if (row < NN) {
            av = *(const uint4*)&attn_b[(size_t)row * DM + (k8 << 3)];
            uint4 a2 = *(const uint4*)&Iw[(size_t)row * DM + (k8 << 3)];
            av.x = addpk(av.x, a2.x); av.y = addpk(av.y, a2.y);
            av.z = addpk(av.z, a2.z); av.w = addpk(av.w, a2.w);
        }
        *(uint4*)(smA + r * 256 + ((k8 << 4) ^ ((r & 7) << 4))) = av;
    }
    stage_w<128, 128>(smW, Wo, t);
    __syncthreads();

    // GEMM1: (attn+Iw) @ Wo^T
    f4 acc1[2][2];
#pragma unroll
    for (int m = 0; m < 2; ++m) { acc1[m][0] = (f4){0,0,0,0}; acc1[m][1] = (f4){0,0,0,0}; }
    mm_tile<2, 4>(smA, smW, 256, wr, wc, lr, lk, acc1);

    // + bo + h residual
    {
        float b_[2] = { bo[gcol[0]], bo[gcol[1]] };
#pragma unroll
        for (int m = 0; m < 2; ++m)
#pragma unroll
            for (int i = 0; i < 4; ++i) {
                int row = n0 + lrow[m][i];
                bool ok = row < NN;
#pragma unroll
                for (int n = 0; n < 2; ++n) {
                    float r = ok ? __bfloat162float(hres[(size_t)row * DM + gcol[n]]) : 0.f;
                    acc1[m][n][i] += b_[n] + r;
                }
            }
    }
    // LN1 stats
#pragma unroll
    for (int m = 0; m < 2; ++m)
#pragma unroll
        for (int i = 0; i < 4; ++i) {
            float s = acc1[m][0][i] + acc1[m][1][i];
            float q = acc1[m][0][i] * acc1[m][0][i] + acc1[m][1][i] * acc1[m][1][i];
            s += __shfl_xor(s, 1); s += __shfl_xor(s, 2); s += __shfl_xor(s, 4); s += __shfl_xor(s, 8);
            q += __shfl_xor(q, 1); q += __shfl_xor(q, 2); q += __shfl_xor(q, 4); q += __shfl_xor(q, 8);
            if (lr == 0) { redS[wc][lrow[m][i]] = s; redQ[wc][lrow[m][i]] = q; }
        }
    __syncthreads();                             // redS visible; A_in/Wo dead
    {
        float gam[2] = { g1v[gcol[0]], g1v[gcol[1]] };
        float bet[2] = { b1v[gcol[0]], b1v[gcol[1]] };
#pragma unroll
        for (int m = 0; m < 2; ++m)
#pragma unroll
            for (int i = 0; i < 4; ++i) {
                int lw = lrow[m][i];
                float s = redS[0][lw] + redS[1][lw] + redS[2][lw] + redS[3][lw];
                float q = redQ[0][lw] + redQ[1][lw] + redQ[2][lw] + redQ[3][lw];
                float mean = s * 0.0078125f;
                float var  = q * 0.0078125f - mean * mean;
                float rstd = rsqrtf(var + 1e-5f);
#pragma unroll
                for (int n = 0; n < 2; ++n)
                    acc1[m][n][i] = (acc1[m][n][i] - mean) * rstd * gam[n] + bet[n];
            }
    }
    // h2 -> LDS (bf16), stage Wf1
#pragma unroll
    for (int m = 0; m < 2; ++m)
#pragma unroll
        for (int i = 0; i < 4; ++i) {
            int rw = lrow[m][i];
#pragma unroll
            for (int n = 0; n < 2; ++n)
                *(unsigned short*)(smA + rw * 256 + ((gcol[n] * 2) ^ ((rw & 7) << 4))) = f2bu(acc1[m][n][i]);
        }
    stage_w<256, 128>(smW, Wf1, t);
    __syncthreads();

    // GEMM2: ffmid = relu(h2 @ Wf1^T + bf1), 64x256
    f4 acc2[2][4];
#pragma unroll
    for (int m = 0; m < 2; ++m)
#pragma unroll
        for (int n = 0; n < 4; ++n) acc2[m][n] = (f4){0,0,0,0};
    mm_tile<4, 4>(smA, smW, 256, wr, wc, lr, lk, acc2);
    {
        int gc2[4];
        float b_[4];
#pragma unroll
        for (int n = 0; n < 4; ++n) { gc2[n] = wc * 64 + n * 16 + lr; b_[n] = bf1[gc2[n]]; }
#pragma unroll
        for (int m = 0; m < 2; ++m)
#pragma unroll
            for (int i = 0; i < 4; ++i) {
                int rw = lrow[m][i];
#pragma unroll
                for (int n = 0; n < 4; ++n) {
                    float v = fmaxf(acc2[m][n][i] + b_[n], 0.f);
                    *(unsigned short*)(smF + rw * 512 + ((gc2[n] * 2) ^ ((rw & 7) << 4))) = f2bu(v);
                }
            }
    }
    __syncthreads();                             // Wf1/h2 dead; ffmid visible
    stage_w<128, 256>(smW, Wf2, t);
    __syncthreads();

    // GEMM3: ff = ffmid @ Wf2^T (K=256); + bf2 + h2(reg) residual; LN2
    f4 acc3[2][2];
#pragma unroll
    for (int m = 0; m < 2; ++m) { acc3[m][0] = (f4){0,0,0,0}; acc3[m][1] = (f4){0,0,0,0}; }
    mm_tile<2, 8>(smF, smW, 512, wr, wc, lr, lk, acc3);
    {
        float b_[2] = { bf2[gcol[0]], bf2[gcol[1]] };
#pragma unroll
        for (int m = 0; m < 2; ++m)
#pragma unroll
            for (int i = 0; i < 4; ++i)
#pragma unroll
                for (int n = 0; n < 2; ++n)
                    acc3[m][n][i] += b_[n] + acc1[m][n][i];
    }
#pragma unroll
    for (int m = 0; m < 2; ++m)
#pragma unroll
        for (int i = 0; i < 4; ++i) {
            float s = acc3[m][0][i] + acc3[m][1][i];
            float q = acc3[m][0][i] * acc3[m][0][i] + acc3[m][1][i] * acc3[m][1][i];
            s += __shfl_xor(s, 1); s += __shfl_xor(s, 2); s += __shfl_xor(s, 4); s += __shfl_xor(s, 8);
            q += __shfl_xor(q, 1); q += __shfl_xor(q, 2); q += __shfl_xor(q, 4); q += __shfl_xor(q, 8);
            if (lr == 0) { redS[wc][lrow[m][i]] = s; redQ[wc][lrow[m][i]] = q; }
        }
    __syncthreads();
    {
        float gam[2] = { g2v[gcol[0]], g2v[gcol[1]] };
        float bet[2] = { b2v[gcol[0]], b2v[gcol[1]] };
#pragma unroll
        for (int m = 0; m < 2; ++m)
#pragma unroll
            for (int i = 0; i < 4; ++i) {
                int lw = lrow[m][i];
                float s = redS[0][lw] + redS[1][lw] + redS[2][lw] + redS[3][lw];
                float q = redQ[0][lw] + redQ[1][lw] + redQ[2][lw] + redQ[3][lw];
                float mean = s * 0.0078125f;
                float var  = q * 0.0078125f - mean * mean;
                float rstd = rsqrtf(var + 1e-5f);
                int row = n0 + lw;
#pragma unroll
                for (int n = 0; n < 2; ++n) {
                    float o = (acc3[m][n][i] - mean) * rstd * gam[n] + bet[n];
                    acc3[m][n][i] = o;
                    if (row < NN) {
                        hres[(size_t)row * DM + gcol[n]] = __float2bfloat16(o);
                        if (hout_f) hout_f[(size_t)row * DM + gcol[n]] = o;
                    }
                }
            }
    }
    __syncthreads();                             // ffmid/Wf2 dead

    if (doQKV) {
        // h_new -> LDS, stage Wq/Wk/Wv
#pragma unroll
        for (int m = 0; m < 2; ++m)
#pragma unroll
            for (int i = 0; i < 4; ++i) {
                int rw = lrow[m][i];
#pragma unroll
                for (int n = 0; n < 2; ++n)
                    *(unsigned short*)(smA + rw * 256 + ((gcol[n] * 2) ^ ((rw & 7) << 4))) = f2bu(acc3[m][n][i]);
            }
        stage_w<128, 128>(smW,          Wq, t);
        stage_w<128, 128>(smW + 32768,  Wk, t);
        stage_w<128, 128>(smW + 65536,  Wv, t);
        __syncthreads();
#pragma unroll
        for (int o = 0; o < 3; ++o) {
            const char* Wp = smW + o * 32768;
            const float* bp = (o == 0) ? bqv : (o == 1) ? bkv : bvv;
            bf16* Cp = (o == 0) ? Qo : (o == 1) ? Ko : Vo;
            f4 aq[2][2];
#pragma unroll
            for (int m = 0; m < 2; ++m) { aq[m][0] = (f4){0,0,0,0}; aq[m][1] = (f4){0,0,0,0}; }
            mm_tile<2, 4>(smA, Wp, 256, wr, wc, lr, lk, aq);
            float b_[2] = { bp[gcol[0]], bp[gcol[1]] };
#pragma unroll
            for (int m = 0; m < 2; ++m)
#pragma unroll
                for (int i = 0; i < 4; ++i) {
                    int row = n0 + lrow[m][i];
                    if (row < NN)
#pragma unroll
                        for (int n = 0; n < 2; ++n)
                            Cp[(size_t)row * DM + gcol[n]] = __float2bfloat16(aq[m][n][i] + b_[n]);
                }
        }
    }
}

// ---------------- edge attention: one wave per dst, 16 lanes per edge ----------------
__global__ __launch_bounds__(256)
void attn_k(const bf16* __restrict__ Q, const bf16* __restrict__ K,
            const bf16* __restrict__ V, const int* __restrict__ row_ptr,
            const int* __restrict__ csr, bf16* __restrict__ out)
{
    int lane = threadIdx.x & 63;
    int n = blockIdx.x * 4 + (threadIdx.x >> 6);
    int g = lane >> 4, sub = lane & 15;
    const uint4* Q4 = (const uint4*)Q;
    const uint4* K4 = (const uint4*)K;
    const uint4* V4 = (const uint4*)V;
    float q[8];
    up8(Q4[n * 16 + sub], q);
    int e0 = row_ptr[n], e1 = row_ptr[n + 1];
    float acc[8] = {0.f, 0.f, 0.f, 0.f, 0.f, 0.f, 0.f, 0.f};
    float zacc = 0.f;

    int e = e0 + g;
    int s0 = (e < e1) ? csr[e] : 0;
    uint4 k0 = K4[(size_t)s0 * 16 + sub];
    uint4 v0 = V4[(size_t)s0 * 16 + sub];
    for (int base = e0; base < e1; base += 4) {
        int en = base + 4 + g;
        int s1 = (en < e1) ? csr[en] : 0;
        uint4 k1 = K4[(size_t)s1 * 16 + sub];
        uint4 v1 = V4[(size_t)s1 * 16 + sub];
        float kf[8];
        up8(k0, kf);
        float p = q[0] * kf[0] + q[1] * kf[1] + q[2] * kf[2] + q[3] * kf[3]
                + q[4] * kf[4] + q[5] * kf[5] + q[6] * kf[6] + q[7] * kf[7];
        p += __shfl_xor(p, 1);
        float sc = __expf(fminf(fmaxf(p * 0.25f, -10.f), 10.f)) * 0.5f;
        if (base + g >= e1) sc = 0.f;
        float vf[8];
        up8(v0, vf);
#pragma unroll
        for (int j = 0; j < 8; ++j) acc[j] = fmaf(sc, vf[j], acc[j]);
        zacc += sc;
        k0 = k1; v0 = v1;
    }
#pragma unroll
    for (int j = 0; j < 8; ++j) {
        acc[j] += __shfl_xor(acc[j], 16);
        acc[j] += __shfl_xor(acc[j], 32);
    }
    zacc += __shfl_xor(zacc, 16);
    zacc += __shfl_xor(zacc, 32);
    float inv = 1.f / (zacc + 1e-6f);
    if (g == 0) {
        uint4 o;
        o.x = pk2(acc[0] * inv, acc[1] * inv);
        o.y = pk2(acc[2] * inv, acc[3] * inv);
        o.z = pk2(acc[4] * inv, acc[5] * inv);
        o.w = pk2(acc[6] * inv, acc[7] * inv);
        ((uint4*)out)[n * 16 + sub] = o;
    }
}

// ---------------- host side ----------------
static inline void g1(hipStream_t st, const bf16* A, const bf16* A2, const bf16* W,
                      const float* bia, float* Cf, bf16* Cb, int N, int K, int M, int post)
{
    dim3 grid((N + 63) / 64, M / 128, 1);
    gemm_k<<<grid, 256, 0, st>>>(A, A2, W, nullptr, nullptr, bia, nullptr, nullptr,
                                 Cf, Cb, nullptr, nullptr, N, K, M, post);
}

static inline void g3(hipStream_t st, const bf16* A,
                      const bf16* W0, const float* b0, bf16* C0,
                      const bf16* W1, const float* b1, bf16* C1,
                      const bf16* W2, const float* b2, bf16* C2,
                      int N, int K, int M)
{
    dim3 grid((N + 63) / 64, M / 128, 3);
    gemm_k<<<grid, 256, 0, st>>>(A, nullptr, W0, W1, W2, b0, b1, b2,
                                 nullptr, C0, C1, C2, N, K, M, 0);
}

extern "C" void kernel_launch(void* const* d_in, const int* in_sizes, int n_in,
                              void* d_out, int out_size, void* d_ws, size_t ws_size,
                              hipStream_t stream)
{
    const float* x    = (const float*)d_in[0];
    const float* Iin  = (const float*)d_in[1];
    const int*   src  = (const int*)d_in[2];
    const int*   dst  = (const int*)d_in[3];
    const float* Wemb = (const float*)d_in[4];
    const float* Wq   = (const float*)d_in[5];  const float* bq  = (const float*)d_in[6];
    const float* Wk   = (const float*)d_in[7];  const float* bk  = (const float*)d_in[8];
    const float* Wv   = (const float*)d_in[9];  const float* bv  = (const float*)d_in[10];
    const float* Wi   = (const float*)d_in[11]; const float* bi  = (const float*)d_in[12];
    const float* Wo   = (const float*)d_in[13]; const float* bo  = (const float*)d_in[14];
    const float* g1g  = (const float*)d_in[15]; const float* be1 = (const float*)d_in[16];
    const float* g2g  = (const float*)d_in[17]; const float* be2 = (const float*)d_in[18];
    const float* Wf1  = (const float*)d_in[19]; const float* bf1 = (const float*)d_in[20];
    const float* Wf2  = (const float*)d_in[21]; const float* bf2 = (const float*)d_in[22];
    const float* Wm1  = (const float*)d_in[23]; const float* bm1 = (const float*)d_in[24];
    const float* Wm2  = (const float*)d_in[25]; const float* bm2 = (const float*)d_in[26];

    const size_t NF = (size_t)NN * DM;          // 2,560,000
    bf16* B      = (bf16*)d_ws;
    bf16* h_b    = B;                           // bf16 residual stream (in-place updated)
    bf16* Qb     = B + NF;
    bf16* Kb     = B + 2 * NF;
    bf16* Vb     = B + 3 * NF;
    bf16* attn_b = B + 4 * NF;
    bf16* Iw_b   = B + 5 * NF;
    bf16* wts    = B + 6 * NF;
    // weight arena offsets (elements)
    bf16* Wemb_b = wts;                 // 32768
    bf16* Wq_b   = wts + 32768;         // 16384
    bf16* Wk_b   = Wq_b + 16384;
    bf16* Wv_b   = Wk_b + 16384;
    bf16* Wo_b   = Wv_b + 16384;
    bf16* Wi_b   = Wo_b + 16384;        // 8192
    bf16* Wf1_b  = Wi_b + 8192;         // 32768
    bf16* Wf2_b  = Wf1_b + 32768;       // 32768
    bf16* Wm1_b  = Wf2_b + 32768;       // 16384
    bf16* Wm2_b  = Wm1_b + 16384;       // 32768
    bf16* wend   = Wm2_b + 32768;
    // aliases over dead regions
    bf16* x_b    = Qb;                  // N x 256 (spans Qb+Kb), dead before QKV0
    bf16* Iin_b  = Vb;                  // N x 64, dead before QKV0
    bf16* tmp_b  = Qb;                  // head mid (N x 128), QKV dead after last layer
    int* ib      = (int*)wend;
    int* cnt     = ib;
    int* cnt2    = ib + NN;
    int* row_ptr = ib + 2 * NN;
    int* csr     = ib + 3 * NN + 1;

    // ---- CSR build (once per call) ----
    hipMemsetAsync(cnt,  0, NN * sizeof(int), stream);
    hipMemsetAsync(cnt2, 0, NN * sizeof(int), stream);
    hist_k<<<(NE + 255) / 256, 256, 0, stream>>>(dst, cnt, NE);
    scan_k<<<1, 1024, 0, stream>>>(cnt, row_ptr, NN);
    scatter_k<<<(NE + 255) / 256, 256, 0, stream>>>(src, dst, row_ptr, cnt2, csr, NE);

    // ---- batched f32->bf16 conversion of x, I, and all weights ----
    Cvt c;
    c.s[0] = x;    c.d[0] = x_b;    c.n[0] = NN * DIN;
    c.s[1] = Iin;  c.d[1] = Iin_b;  c.n[1] = NN * 64;
    c.s[2] = Wemb; c.d[2] = Wemb_b; c.n[2] = 32768;
    c.s[3] = Wq;   c.d[3] = Wq_b;   c.n[3] = 16384;
    c.s[4] = Wk;   c.d[4] = Wk_b;   c.n[4] = 16384;
    c.s[5] = Wv;   c.d[5] = Wv_b;   c.n[5] = 16384;
    c.s[6] = Wo;   c.d[6] = Wo_b;   c.n[6] = 16384;
    c.s[7] = Wi;   c.d[7] = Wi_b;   c.n[7] = 8192;
    c.s[8] = Wf1;  c.d[8] = Wf1_b;  c.n[8] = 32768;
    c.s[9] = Wf2;  c.d[9] = Wf2_b;  c.n[9] = 32768;
    c.s[10] = Wm1; c.d[10] = Wm1_b; c.n[10] = 16384;
    c.s[11] = Wm2; c.d[11] = Wm2_b; c.n[11] = 32768;
    cvt_many_k<<<dim3(640, 12), 256, 0, stream>>>(c);

    // ---- prologue: embed, Iw, first-layer QKV ----
    g1(stream, x_b,   nullptr, Wemb_b, nullptr, nullptr, h_b, NN, DIN, DM, 0);
    g1(stream, Iin_b, nullptr, Wi_b, bi, nullptr, Iw_b, NN, 64, DM, 0);
    g3(stream, h_b, Wq_b, bq, Qb, Wk_b, bk, Kb, Wv_b, bv, Vb, NN, DM, DM);

    // ---- 10 shared-weight layers: attn + mega-fused ----
    const int nblk = (NN + 63) / 64;
    for (int l = 0; l < 10; ++l) {
        attn_k<<<NN / 4, 256, 0, stream>>>(Qb, Kb, Vb, row_ptr, csr, attn_b);
        layer_k<<<nblk, 512, 114688, stream>>>(
            attn_b, Iw_b, h_b, (l == 9) ? (float*)d_out : nullptr,
            Qb, Kb, Vb, (l < 9) ? 1 : 0,
            Wo_b, bo, Wf1_b, bf1, Wf2_b, bf2,
            Wq_b, bq, Wk_b, bk, Wv_b, bv,
            g1g, be1, g2g, be2);
    }

    // ---- reconstruction head ----
    g1(stream, h_b, nullptr, Wm1_b, bm1, nullptr, tmp_b, NN, DM, DM, 2);   // selu
    float* xhat = (float*)d_out + NF;
    g1(stream, tmp_b, nullptr, Wm2_b, bm2, xhat, nullptr, NN, DM, DIN, 0);
}